// Round 1
// baseline (2524.642 us; speedup 1.0000x reference)
//
#include <hip/hip_runtime.h>
#include <math.h>

#define B_  2
#define T_  2048
#define D_  1024
#define H_  16
#define DK_ 64
#define FF_ 4096
#define BT_ (B_*T_)

// ---------------------------------------------------------------------------
// K1: fused QKV projection.  q[b,h,t,k] = sum_d x[b,t,d] * Wq[h,d,k]  (same k,v)
// grid: (T/64, 3*B*H), block 256.  64x64 output tile, K=D=1024, BK=32.
// ---------------------------------------------------------------------------
__global__ __launch_bounds__(256) void qkv_kernel(
    const float* __restrict__ x, const float* __restrict__ Wq,
    const float* __restrict__ Wk, const float* __restrict__ Wv,
    float* __restrict__ q, float* __restrict__ k, float* __restrict__ v)
{
    int mat = blockIdx.y / (B_*H_);
    int bh  = blockIdx.y % (B_*H_);
    int b = bh / H_, h = bh % H_;
    const float* W = (mat == 0 ? Wq : (mat == 1 ? Wk : Wv)) + (size_t)h * D_ * DK_;
    float* outp    = (mat == 0 ? q  : (mat == 1 ? k  : v )) + (size_t)bh * T_ * DK_;
    const float* A = x + (size_t)b * T_ * D_ + (size_t)blockIdx.x * 64 * D_;
    float* C = outp + (size_t)blockIdx.x * 64 * DK_;

    __shared__ float as[64][33];   // pad: avoid 4-way bank conflict on row reads
    __shared__ float bs[32][64];
    int tid = threadIdx.x;
    int tx = tid & 15, ty = tid >> 4;
    float acc[4][4] = {};
    for (int k0 = 0; k0 < D_; k0 += 32) {
        int ar = tid >> 3, ac = (tid & 7) * 4;
        #pragma unroll
        for (int p = 0; p < 2; ++p) {
            float4 t4 = *(const float4*)(A + (size_t)(ar + p*32) * D_ + k0 + ac);
            as[ar+p*32][ac+0] = t4.x; as[ar+p*32][ac+1] = t4.y;
            as[ar+p*32][ac+2] = t4.z; as[ar+p*32][ac+3] = t4.w;
        }
        int br = tid >> 4, bc = (tid & 15) * 4;
        #pragma unroll
        for (int p = 0; p < 2; ++p) {
            float4 t4 = *(const float4*)(W + (size_t)(k0 + br + p*16) * DK_ + bc);
            *(float4*)&bs[br+p*16][bc] = t4;
        }
        __syncthreads();
        #pragma unroll
        for (int kk = 0; kk < 32; ++kk) {
            float a[4], bb[4];
            #pragma unroll
            for (int i = 0; i < 4; ++i) a[i] = as[ty*4+i][kk];
            #pragma unroll
            for (int j = 0; j < 4; ++j) bb[j] = bs[kk][tx*4+j];
            #pragma unroll
            for (int i = 0; i < 4; ++i)
                #pragma unroll
                for (int j = 0; j < 4; ++j) acc[i][j] += a[i] * bb[j];
        }
        __syncthreads();
    }
    #pragma unroll
    for (int i = 0; i < 4; ++i)
        #pragma unroll
        for (int j = 0; j < 4; ++j)
            C[(size_t)(ty*4+i) * DK_ + tx*4+j] = acc[i][j];
}

// ---------------------------------------------------------------------------
// K2: colsum[s] = sum_q exp(q[q,:]·k[s,:] / 8)   (softmax over QUERY axis)
// grid: (T/64 s-tiles, B*H), block 256.
// ---------------------------------------------------------------------------
__global__ __launch_bounds__(256) void colsum_kernel(
    const float* __restrict__ q, const float* __restrict__ k,
    float* __restrict__ colsum)
{
    int bh = blockIdx.y;
    int s0 = blockIdx.x * 64;
    const float* qb = q + (size_t)bh * T_ * DK_;
    const float* kb = k + (size_t)bh * T_ * DK_;
    __shared__ float ks[64][65];
    __shared__ float qs[64][65];
    __shared__ float red[16][64];
    int tid = threadIdx.x, tx = tid & 15, ty = tid >> 4;

    for (int i = tid; i < 64*16; i += 256) {
        int row = i >> 4, c = (i & 15) * 4;
        float4 t4 = *(const float4*)(kb + (size_t)(s0+row) * DK_ + c);
        ks[row][c]=t4.x; ks[row][c+1]=t4.y; ks[row][c+2]=t4.z; ks[row][c+3]=t4.w;
    }
    float acc[4] = {0.f, 0.f, 0.f, 0.f};
    for (int qt = 0; qt < T_/64; ++qt) {
        __syncthreads();
        for (int i = tid; i < 64*16; i += 256) {
            int row = i >> 4, c = (i & 15) * 4;
            float4 t4 = *(const float4*)(qb + (size_t)(qt*64+row) * DK_ + c);
            qs[row][c]=t4.x; qs[row][c+1]=t4.y; qs[row][c+2]=t4.z; qs[row][c+3]=t4.w;
        }
        __syncthreads();
        float sc[4][4] = {};
        #pragma unroll
        for (int d = 0; d < 64; ++d) {
            float a[4], bb[4];
            #pragma unroll
            for (int i = 0; i < 4; ++i) a[i]  = qs[ty*4+i][d];
            #pragma unroll
            for (int j = 0; j < 4; ++j) bb[j] = ks[tx*4+j][d];
            #pragma unroll
            for (int i = 0; i < 4; ++i)
                #pragma unroll
                for (int j = 0; j < 4; ++j) sc[i][j] += a[i] * bb[j];
        }
        #pragma unroll
        for (int i = 0; i < 4; ++i)
            #pragma unroll
            for (int j = 0; j < 4; ++j) acc[j] += __expf(sc[i][j] * 0.125f);
    }
    __syncthreads();
    #pragma unroll
    for (int j = 0; j < 4; ++j) red[ty][tx*4+j] = acc[j];
    __syncthreads();
    if (tid < 64) {
        float s = 0.f;
        #pragma unroll
        for (int r = 0; r < 16; ++r) s += red[r][tid];
        colsum[(size_t)bh * T_ + s0 + tid] = s;
    }
}

// ---------------------------------------------------------------------------
// K3: o[q,:] = sum_s exp(score[q,s]) * (v[s,:] / colsum[s]); write to
// attn_o[b][t][h*64+dv].  grid: (T/64 q-tiles, B*H), block 256.
// ---------------------------------------------------------------------------
__global__ __launch_bounds__(256) void attn_pv_kernel(
    const float* __restrict__ q, const float* __restrict__ k,
    const float* __restrict__ v, const float* __restrict__ colsum,
    float* __restrict__ attn_o)
{
    int bh = blockIdx.y, b = bh / H_, h = bh % H_;
    int q0 = blockIdx.x * 64;
    const float* qb = q + (size_t)bh * T_ * DK_;
    const float* kb = k + (size_t)bh * T_ * DK_;
    const float* vb = v + (size_t)bh * T_ * DK_;
    __shared__ float qs[64][65], ks[64][65], vs[64][65], es[64][65];
    __shared__ float rcs[64];
    int tid = threadIdx.x, tx = tid & 15, ty = tid >> 4;

    for (int i = tid; i < 64*16; i += 256) {
        int row = i >> 4, c = (i & 15) * 4;
        float4 t4 = *(const float4*)(qb + (size_t)(q0+row) * DK_ + c);
        qs[row][c]=t4.x; qs[row][c+1]=t4.y; qs[row][c+2]=t4.z; qs[row][c+3]=t4.w;
    }
    float acc[4][4] = {};
    for (int st = 0; st < T_/64; ++st) {
        int s0 = st * 64;
        __syncthreads();   // protect ks/vs/rcs/es from previous iteration readers
        if (tid < 64) rcs[tid] = 1.0f / colsum[(size_t)bh * T_ + s0 + tid];
        for (int i = tid; i < 64*16; i += 256) {
            int row = i >> 4, c = (i & 15) * 4;
            float4 t4 = *(const float4*)(kb + (size_t)(s0+row) * DK_ + c);
            ks[row][c]=t4.x; ks[row][c+1]=t4.y; ks[row][c+2]=t4.z; ks[row][c+3]=t4.w;
            float4 u4 = *(const float4*)(vb + (size_t)(s0+row) * DK_ + c);
            vs[row][c]=u4.x; vs[row][c+1]=u4.y; vs[row][c+2]=u4.z; vs[row][c+3]=u4.w;
        }
        __syncthreads();
        float sc[4][4] = {};
        #pragma unroll
        for (int d = 0; d < 64; ++d) {
            float a[4], bb[4];
            #pragma unroll
            for (int i = 0; i < 4; ++i) a[i]  = qs[ty*4+i][d];
            #pragma unroll
            for (int j = 0; j < 4; ++j) bb[j] = ks[tx*4+j][d];
            #pragma unroll
            for (int i = 0; i < 4; ++i)
                #pragma unroll
                for (int j = 0; j < 4; ++j) sc[i][j] += a[i] * bb[j];
        }
        #pragma unroll
        for (int i = 0; i < 4; ++i)
            #pragma unroll
            for (int j = 0; j < 4; ++j)
                es[ty*4+i][tx*4+j] = __expf(sc[i][j] * 0.125f) * rcs[tx*4+j];
        __syncthreads();
        #pragma unroll
        for (int ss = 0; ss < 64; ++ss) {
            float a[4], bb[4];
            #pragma unroll
            for (int i = 0; i < 4; ++i) a[i]  = es[ty*4+i][ss];
            #pragma unroll
            for (int j = 0; j < 4; ++j) bb[j] = vs[ss][tx*4+j];
            #pragma unroll
            for (int i = 0; i < 4; ++i)
                #pragma unroll
                for (int j = 0; j < 4; ++j) acc[i][j] += a[i] * bb[j];
        }
    }
    #pragma unroll
    for (int i = 0; i < 4; ++i)
        #pragma unroll
        for (int j = 0; j < 4; ++j)
            attn_o[(size_t)(b*T_ + q0 + ty*4+i) * D_ + h*DK_ + tx*4+j] = acc[i][j];
}

// ---------------------------------------------------------------------------
// Generic fp32 GEMM: C = A[M,K] @ B[K,N] (+bias) (+resid) (+relu), 64x64 tiles.
// grid: (N/64, M/64), block 256.
// ---------------------------------------------------------------------------
__global__ __launch_bounds__(256) void gemm64_kernel(
    const float* __restrict__ A, int lda,
    const float* __restrict__ Bw, int ldb,
    float* __restrict__ C, int ldc, int K,
    const float* __restrict__ bias,
    const float* __restrict__ resid, int fuse_relu)
{
    int row0 = blockIdx.y * 64, col0 = blockIdx.x * 64;
    A  += (size_t)row0 * lda;
    Bw += col0;
    C  += (size_t)row0 * ldc + col0;
    if (resid) resid += (size_t)row0 * ldc + col0;
    if (bias)  bias  += col0;

    __shared__ float as[64][33];
    __shared__ float bs[32][64];
    int tid = threadIdx.x;
    int tx = tid & 15, ty = tid >> 4;
    float acc[4][4] = {};
    for (int k0 = 0; k0 < K; k0 += 32) {
        int ar = tid >> 3, ac = (tid & 7) * 4;
        #pragma unroll
        for (int p = 0; p < 2; ++p) {
            float4 t4 = *(const float4*)(A + (size_t)(ar + p*32) * lda + k0 + ac);
            as[ar+p*32][ac+0] = t4.x; as[ar+p*32][ac+1] = t4.y;
            as[ar+p*32][ac+2] = t4.z; as[ar+p*32][ac+3] = t4.w;
        }
        int br = tid >> 4, bc = (tid & 15) * 4;
        #pragma unroll
        for (int p = 0; p < 2; ++p) {
            float4 t4 = *(const float4*)(Bw + (size_t)(k0 + br + p*16) * ldb + bc);
            *(float4*)&bs[br+p*16][bc] = t4;
        }
        __syncthreads();
        #pragma unroll
        for (int kk = 0; kk < 32; ++kk) {
            float a[4], bb[4];
            #pragma unroll
            for (int i = 0; i < 4; ++i) a[i]  = as[ty*4+i][kk];
            #pragma unroll
            for (int j = 0; j < 4; ++j) bb[j] = bs[kk][tx*4+j];
            #pragma unroll
            for (int i = 0; i < 4; ++i)
                #pragma unroll
                for (int j = 0; j < 4; ++j) acc[i][j] += a[i] * bb[j];
        }
        __syncthreads();
    }
    #pragma unroll
    for (int i = 0; i < 4; ++i)
        #pragma unroll
        for (int j = 0; j < 4; ++j) {
            float val = acc[i][j];
            if (bias)  val += bias[tx*4+j];
            if (resid) val += resid[(size_t)(ty*4+i) * ldc + tx*4+j];
            if (fuse_relu) val = fmaxf(val, 0.f);
            C[(size_t)(ty*4+i) * ldc + tx*4+j] = val;
        }
}

// ---------------------------------------------------------------------------
// Norm: out = (y - mean) / sqrt(sum((y-mean)^2)/(D-1))   (Bessel, no eps)
// grid: (BT), block 256, 4 elems/thread.
// ---------------------------------------------------------------------------
__device__ __forceinline__ float block_reduce_sum_256(float v, float* tmp)
{
    #pragma unroll
    for (int off = 32; off; off >>= 1) v += __shfl_down(v, off, 64);
    int lane = threadIdx.x & 63, w = threadIdx.x >> 6;
    __syncthreads();                 // protect tmp reuse across calls
    if (lane == 0) tmp[w] = v;
    __syncthreads();
    return tmp[0] + tmp[1] + tmp[2] + tmp[3];
}

__global__ __launch_bounds__(256) void norm_kernel(
    const float* __restrict__ in, float* __restrict__ outp)
{
    __shared__ float tmp[4];
    int row = blockIdx.x;
    const float* r = in + (size_t)row * D_;
    int tid = threadIdx.x;
    float vals[4];
    #pragma unroll
    for (int i = 0; i < 4; ++i) vals[i] = r[tid + i*256];
    float s = vals[0] + vals[1] + vals[2] + vals[3];
    s = block_reduce_sum_256(s, tmp);
    float m = s * (1.0f / (float)D_);
    float sq = 0.f;
    #pragma unroll
    for (int i = 0; i < 4; ++i) { float c = vals[i] - m; sq += c * c; }
    sq = block_reduce_sum_256(sq, tmp);
    float rs = rsqrtf(sq * (1.0f / (float)(D_ - 1)));
    float* o = outp + (size_t)row * D_;
    #pragma unroll
    for (int i = 0; i < 4; ++i) o[tid + i*256] = (vals[i] - m) * rs;
}

// ---------------------------------------------------------------------------
extern "C" void kernel_launch(void* const* d_in, const int* in_sizes, int n_in,
                              void* d_out, int out_size, void* d_ws, size_t ws_size,
                              hipStream_t stream)
{
    const float* x  = (const float*)d_in[0];
    const float* Wq = (const float*)d_in[1];
    const float* Wk = (const float*)d_in[2];
    const float* Wv = (const float*)d_in[3];
    const float* Wo = (const float*)d_in[4];
    const float* W1 = (const float*)d_in[5];
    const float* b1 = (const float*)d_in[6];
    const float* W2 = (const float*)d_in[7];
    const float* b2 = (const float*)d_in[8];
    float* out = (float*)d_out;
    float* ws  = (float*)d_ws;

    const size_t SZ = (size_t)BT_ * D_;          // 4,194,304 elems
    float* q      = ws;                          // [B,H,T,DK]
    float* k      = ws + SZ;
    float* v      = ws + 2*SZ;
    float* attn_o = ws + 3*SZ;                   // [B,T,H*DV]
    float* colsum = ws + 4*SZ;                   // [B,H,T]
    float* hid    = colsum + (size_t)B_*H_*T_;   // [BT,FF]
    // buffer reuse after attention is consumed:
    float* oproj  = q;                           // o@Wo + x
    float* out1   = k;                           // norm1 output
    float* ffout  = v;                           // ffn + out1 (pre-norm2)
    // total ws: (4*SZ + 65536 + BT*FF)*4B ≈ 134.5 MB

    qkv_kernel<<<dim3(T_/64, 3*B_*H_), 256, 0, stream>>>(x, Wq, Wk, Wv, q, k, v);
    colsum_kernel<<<dim3(T_/64, B_*H_), 256, 0, stream>>>(q, k, colsum);
    attn_pv_kernel<<<dim3(T_/64, B_*H_), 256, 0, stream>>>(q, k, v, colsum, attn_o);
    gemm64_kernel<<<dim3(D_/64, BT_/64), 256, 0, stream>>>(
        attn_o, D_, Wo, D_, oproj, D_, D_, nullptr, x, 0);
    norm_kernel<<<dim3(BT_), 256, 0, stream>>>(oproj, out1);
    gemm64_kernel<<<dim3(FF_/64, BT_/64), 256, 0, stream>>>(
        out1, D_, W1, FF_, hid, FF_, D_, b1, nullptr, 1);
    gemm64_kernel<<<dim3(D_/64, BT_/64), 256, 0, stream>>>(
        hid, FF_, W2, D_, ffout, D_, FF_, b2, out1, 0);
    norm_kernel<<<dim3(BT_), 256, 0, stream>>>(ffout, out);
}

// Round 2
// 522.621 us; speedup vs baseline: 4.8307x; 4.8307x over previous
//
#include <hip/hip_runtime.h>
#include <hip/hip_bf16.h>
#include <math.h>

#define B_  2
#define T_  2048
#define D_  1024
#define H_  16
#define DK_ 64
#define FF_ 4096
#define BT_ (B_*T_)

typedef __attribute__((ext_vector_type(8))) short bf16x8;
typedef __attribute__((ext_vector_type(4))) float f32x4;

__device__ __forceinline__ ushort f2bf(float f) {
    __hip_bfloat16 h = __float2bfloat16(f);
    return *reinterpret_cast<ushort*>(&h);
}
__device__ __forceinline__ float bf2f(ushort u) {
    __hip_bfloat16 h;
    *reinterpret_cast<ushort*>(&h) = u;
    return __bfloat162float(h);
}

// ---------------------------------------------------------------------------
// f32 -> bf16 elementwise (vectorized, n multiple of 1024)
// ---------------------------------------------------------------------------
__global__ __launch_bounds__(256) void cvt_bf16_kernel(
    const float* __restrict__ in, ushort* __restrict__ out, int n)
{
    int i = (blockIdx.x * 256 + threadIdx.x) * 4;
    if (i >= n) return;
    float4 v = *(const float4*)(in + i);
    ushort4 o;
    o.x = f2bf(v.x); o.y = f2bf(v.y); o.z = f2bf(v.z); o.w = f2bf(v.w);
    *(ushort4*)(out + i) = o;
}

// ---------------------------------------------------------------------------
// transpose + convert: in f32 [K][N] -> out bf16 [N][K]; batched over z.
// ---------------------------------------------------------------------------
__global__ __launch_bounds__(256) void transpose_bf16_kernel(
    const float* __restrict__ in, ushort* __restrict__ out,
    int K, int N, long in_bstride, long out_bstride)
{
    __shared__ float t[32][33];
    const float* ib = in + (size_t)blockIdx.z * in_bstride;
    ushort* ob = out + (size_t)blockIdx.z * out_bstride;
    int n0 = blockIdx.x * 32, k0 = blockIdx.y * 32;
    int tid = threadIdx.x;
    int r = tid >> 3, c4 = (tid & 7) * 4;
    float4 v = *(const float4*)(ib + (size_t)(k0 + r) * N + n0 + c4);
    t[r][c4] = v.x; t[r][c4+1] = v.y; t[r][c4+2] = v.z; t[r][c4+3] = v.w;
    __syncthreads();
    int n = tid >> 3, kc = (tid & 7) * 4;
    ushort4 o;
    o.x = f2bf(t[kc+0][n]); o.y = f2bf(t[kc+1][n]);
    o.z = f2bf(t[kc+2][n]); o.w = f2bf(t[kc+3][n]);
    *(ushort4*)(ob + (size_t)(n0 + n) * K + k0 + kc) = o;
}

// ---------------------------------------------------------------------------
// NT GEMM, bf16 MFMA: C[M][N] = A[M][K] @ Bt[N][K]^T  (+bias +resid +relu)
// 128x128 tile, BK=32, 256 threads (4 waves, 2x2 quadrants of 64x64).
// ---------------------------------------------------------------------------
template<int OUT_BF16>
__global__ __launch_bounds__(256) void gemm_nt_kernel(
    const ushort* __restrict__ A, int lda,
    const ushort* __restrict__ Bt, int ldb,
    void* __restrict__ C, int ldc, int K,
    const float* __restrict__ bias,
    const float* __restrict__ resid, int relu)
{
    __shared__ __attribute__((aligned(16))) ushort As[4][128][8];
    __shared__ __attribute__((aligned(16))) ushort Bs[4][128][8];
    int row0 = blockIdx.y * 128, col0 = blockIdx.x * 128;
    int tid = threadIdx.x;
    int w = tid >> 6, l = tid & 63;
    int wr = (w >> 1) * 64, wc = (w & 1) * 64;

    f32x4 acc[4][4];
    #pragma unroll
    for (int i = 0; i < 4; ++i)
        #pragma unroll
        for (int j = 0; j < 4; ++j) acc[i][j] = (f32x4){0.f, 0.f, 0.f, 0.f};

    for (int k0 = 0; k0 < K; k0 += 32) {
        __syncthreads();
        #pragma unroll
        for (int p = 0; p < 2; ++p) {
            int idx = tid + p * 256;
            int m = idx & 127, kc = idx >> 7;
            *(uint4*)&As[kc][m][0] =
                *(const uint4*)(A + (size_t)(row0 + m) * lda + k0 + kc * 8);
            *(uint4*)&Bs[kc][m][0] =
                *(const uint4*)(Bt + (size_t)(col0 + m) * ldb + k0 + kc * 8);
        }
        __syncthreads();
        int kc = l >> 4;
        bf16x8 af[4], bfr[4];
        #pragma unroll
        for (int i = 0; i < 4; ++i)
            af[i] = *(const bf16x8*)&As[kc][wr + i*16 + (l & 15)][0];
        #pragma unroll
        for (int j = 0; j < 4; ++j)
            bfr[j] = *(const bf16x8*)&Bs[kc][wc + j*16 + (l & 15)][0];
        #pragma unroll
        for (int i = 0; i < 4; ++i)
            #pragma unroll
            for (int j = 0; j < 4; ++j)
                acc[i][j] = __builtin_amdgcn_mfma_f32_16x16x32_bf16(
                    af[i], bfr[j], acc[i][j], 0, 0, 0);
    }

    #pragma unroll
    for (int i = 0; i < 4; ++i) {
        int rbase = row0 + wr + i*16 + (l >> 4) * 4;
        #pragma unroll
        for (int j = 0; j < 4; ++j) {
            int col = col0 + wc + j*16 + (l & 15);
            float bv = bias ? bias[col] : 0.f;
            #pragma unroll
            for (int r = 0; r < 4; ++r) {
                int row = rbase + r;
                float val = acc[i][j][r] + bv;
                if (resid) val += resid[(size_t)row * ldc + col];
                if (relu)  val = fmaxf(val, 0.f);
                if (OUT_BF16) ((ushort*)C)[(size_t)row * ldc + col] = f2bf(val);
                else          ((float*)C)[(size_t)row * ldc + col]  = val;
            }
        }
    }
}

// ---------------------------------------------------------------------------
// colsum[s] = sum_q exp(q·k/8).  grid (T/128, B*H), 256 thr.
// qkv packed [bt][3072]: q at col 0, k at 1024, v at 2048 (+h*64).
// ---------------------------------------------------------------------------
__global__ __launch_bounds__(256) void csum_kernel(
    const ushort* __restrict__ qkv, float* __restrict__ col_sum)
{
    int bh = blockIdx.y, b = bh >> 4, h = bh & 15;
    int s0 = blockIdx.x * 128;
    const ushort* qb = qkv + (size_t)b * T_ * 3072 + h * 64;
    const ushort* kb = qb + 1024;
    __shared__ __attribute__((aligned(16))) ushort Ks[8][128][8];
    __shared__ __attribute__((aligned(16))) ushort Qs[8][64][8];
    int tid = threadIdx.x, w = tid >> 6, l = tid & 63;
    int scol = w * 32;

    #pragma unroll
    for (int p = 0; p < 4; ++p) {
        int idx = tid + p * 256;
        int s = idx & 127, kc = idx >> 7;
        *(uint4*)&Ks[kc][s][0] =
            *(const uint4*)(kb + (size_t)(s0 + s) * 3072 + kc * 8);
    }
    float cs[2] = {0.f, 0.f};
    for (int qt = 0; qt < T_ / 64; ++qt) {
        __syncthreads();
        #pragma unroll
        for (int p = 0; p < 2; ++p) {
            int idx = tid + p * 256;
            int qq = idx & 63, kc = idx >> 6;
            *(uint4*)&Qs[kc][qq][0] =
                *(const uint4*)(qb + (size_t)(qt*64 + qq) * 3072 + kc * 8);
        }
        __syncthreads();
        bf16x8 af[4][2], bfr[2][2];
        #pragma unroll
        for (int qi = 0; qi < 4; ++qi)
            #pragma unroll
            for (int ks = 0; ks < 2; ++ks)
                af[qi][ks] = *(const bf16x8*)&Qs[ks*4 + (l>>4)][qi*16 + (l & 15)][0];
        #pragma unroll
        for (int sj = 0; sj < 2; ++sj)
            #pragma unroll
            for (int ks = 0; ks < 2; ++ks)
                bfr[sj][ks] = *(const bf16x8*)&Ks[ks*4 + (l>>4)][scol + sj*16 + (l & 15)][0];
        #pragma unroll
        for (int qi = 0; qi < 4; ++qi)
            #pragma unroll
            for (int sj = 0; sj < 2; ++sj) {
                f32x4 d = (f32x4){0.f, 0.f, 0.f, 0.f};
                #pragma unroll
                for (int ks = 0; ks < 2; ++ks)
                    d = __builtin_amdgcn_mfma_f32_16x16x32_bf16(
                        af[qi][ks], bfr[sj][ks], d, 0, 0, 0);
                cs[sj] += __expf(d[0]*0.125f) + __expf(d[1]*0.125f)
                        + __expf(d[2]*0.125f) + __expf(d[3]*0.125f);
            }
    }
    #pragma unroll
    for (int sj = 0; sj < 2; ++sj) {
        float v = cs[sj];
        v += __shfl_down(v, 32, 64);
        v += __shfl_down(v, 16, 64);
        if (l < 16)
            col_sum[(size_t)bh * T_ + s0 + scol + sj*16 + l] = v;
    }
}

// ---------------------------------------------------------------------------
// vt[bh][dv][s] = v[bh][s][dv] / colsum[bh][s]   (bf16, transposed V)
// grid (T/64, B*H), 256 thr.
// ---------------------------------------------------------------------------
__global__ __launch_bounds__(256) void vscale_kernel(
    const ushort* __restrict__ qkv, const float* __restrict__ col_sum,
    ushort* __restrict__ vt)
{
    int bh = blockIdx.y, b = bh >> 4, h = bh & 15;
    int s0 = blockIdx.x * 64;
    const ushort* vb = qkv + (size_t)b * T_ * 3072 + 2048 + h * 64;
    __shared__ float t[64][65];
    int tid = threadIdx.x;
    #pragma unroll
    for (int p = 0; p < 2; ++p) {
        int idx = tid + p * 256;
        int s = idx >> 3, c0 = (idx & 7) * 8;
        uint4 raw = *(const uint4*)(vb + (size_t)(s0 + s) * 3072 + c0);
        float rc = 1.0f / col_sum[(size_t)bh * T_ + s0 + s];
        ushort* u = (ushort*)&raw;
        #pragma unroll
        for (int i = 0; i < 8; ++i) t[s][c0 + i] = bf2f(u[i]) * rc;
    }
    __syncthreads();
    #pragma unroll
    for (int p = 0; p < 2; ++p) {
        int idx = tid + p * 256;
        int dv = idx >> 3, sc = (idx & 7) * 8;
        ushort o[8];
        #pragma unroll
        for (int i = 0; i < 8; ++i) o[i] = f2bf(t[sc + i][dv]);
        *(uint4*)(vt + ((size_t)bh * 64 + dv) * T_ + s0 + sc) = *(uint4*)o;
    }
}

// ---------------------------------------------------------------------------
// PV: O[q][dv] = sum_s exp(q·k/8) * vt[dv][s].  grid (T/64, B*H), 256 thr.
// Each wave owns 16 q-rows; E tile is wave-private in LDS (no extra barrier).
// ---------------------------------------------------------------------------
__global__ __launch_bounds__(256) void attn_pv_kernel(
    const ushort* __restrict__ qkv, const ushort* __restrict__ vt,
    ushort* __restrict__ attn_o)
{
    int bh = blockIdx.y, b = bh >> 4, h = bh & 15;
    int q0 = blockIdx.x * 64;
    const ushort* qb = qkv + (size_t)b * T_ * 3072 + h * 64;
    const ushort* kb = qb + 1024;
    const ushort* vtb = vt + (size_t)bh * 64 * T_;
    __shared__ __attribute__((aligned(16))) ushort Qs[8][64][8];
    __shared__ __attribute__((aligned(16))) ushort Ks[8][64][8];
    __shared__ __attribute__((aligned(16))) ushort Vs[8][64][8];
    __shared__ __attribute__((aligned(16))) ushort Es[8][64][8];
    int tid = threadIdx.x, w = tid >> 6, l = tid & 63;
    int qw = w * 16;

    #pragma unroll
    for (int p = 0; p < 2; ++p) {
        int idx = tid + p * 256;
        int qq = idx & 63, kc = idx >> 6;
        *(uint4*)&Qs[kc][qq][0] =
            *(const uint4*)(qb + (size_t)(q0 + qq) * 3072 + kc * 8);
    }
    __syncthreads();
    bf16x8 qf[2];
    #pragma unroll
    for (int ks = 0; ks < 2; ++ks)
        qf[ks] = *(const bf16x8*)&Qs[ks*4 + (l>>4)][qw + (l & 15)][0];

    f32x4 oacc[4];
    #pragma unroll
    for (int j = 0; j < 4; ++j) oacc[j] = (f32x4){0.f, 0.f, 0.f, 0.f};

    for (int st = 0; st < T_ / 64; ++st) {
        int s0 = st * 64;
        __syncthreads();
        #pragma unroll
        for (int p = 0; p < 2; ++p) {
            int idx = tid + p * 256;
            int rr = idx & 63, kc = idx >> 6;
            *(uint4*)&Ks[kc][rr][0] =
                *(const uint4*)(kb + (size_t)(s0 + rr) * 3072 + kc * 8);
            *(uint4*)&Vs[kc][rr][0] =
                *(const uint4*)(vtb + (size_t)rr * T_ + s0 + kc * 8);
        }
        __syncthreads();
        // QK^T -> exp -> Es (wave-private q rows)
        #pragma unroll
        for (int sj = 0; sj < 4; ++sj) {
            f32x4 d = (f32x4){0.f, 0.f, 0.f, 0.f};
            #pragma unroll
            for (int ks = 0; ks < 2; ++ks) {
                bf16x8 kf = *(const bf16x8*)&Ks[ks*4 + (l>>4)][sj*16 + (l & 15)][0];
                d = __builtin_amdgcn_mfma_f32_16x16x32_bf16(qf[ks], kf, d, 0, 0, 0);
            }
            #pragma unroll
            for (int r = 0; r < 4; ++r) {
                int qq = qw + (l>>4)*4 + r;
                int ss = sj*16 + (l & 15);
                Es[ss >> 3][qq][ss & 7] = f2bf(__expf(d[r] * 0.125f));
            }
        }
        // PV
        bf16x8 ef[2];
        #pragma unroll
        for (int ks = 0; ks < 2; ++ks)
            ef[ks] = *(const bf16x8*)&Es[ks*4 + (l>>4)][qw + (l & 15)][0];
        #pragma unroll
        for (int j = 0; j < 4; ++j)
            #pragma unroll
            for (int ks = 0; ks < 2; ++ks) {
                bf16x8 vf = *(const bf16x8*)&Vs[ks*4 + (l>>4)][j*16 + (l & 15)][0];
                oacc[j] = __builtin_amdgcn_mfma_f32_16x16x32_bf16(ef[ks], vf, oacc[j], 0, 0, 0);
            }
    }
    #pragma unroll
    for (int j = 0; j < 4; ++j)
        #pragma unroll
        for (int r = 0; r < 4; ++r) {
            int qq = q0 + qw + (l>>4)*4 + r;
            int dv = j*16 + (l & 15);
            attn_o[(size_t)(b*T_ + qq) * 1024 + h*64 + dv] = f2bf(oacc[j][r]);
        }
}

// ---------------------------------------------------------------------------
// mean/std norm (Bessel), optional bf16 side-output.
// ---------------------------------------------------------------------------
__device__ __forceinline__ float block_reduce_sum_256(float v, float* tmp)
{
    #pragma unroll
    for (int off = 32; off; off >>= 1) v += __shfl_down(v, off, 64);
    int lane = threadIdx.x & 63, w = threadIdx.x >> 6;
    __syncthreads();
    if (lane == 0) tmp[w] = v;
    __syncthreads();
    return tmp[0] + tmp[1] + tmp[2] + tmp[3];
}

__global__ __launch_bounds__(256) void norm_kernel(
    const float* __restrict__ in, float* __restrict__ outf,
    ushort* __restrict__ outb)
{
    __shared__ float tmp[4];
    int row = blockIdx.x;
    const float* r = in + (size_t)row * D_;
    int tid = threadIdx.x;
    float vals[4];
    #pragma unroll
    for (int i = 0; i < 4; ++i) vals[i] = r[tid + i*256];
    float s = vals[0] + vals[1] + vals[2] + vals[3];
    s = block_reduce_sum_256(s, tmp);
    float m = s * (1.0f / (float)D_);
    float sq = 0.f;
    #pragma unroll
    for (int i = 0; i < 4; ++i) { float c = vals[i] - m; sq += c * c; }
    sq = block_reduce_sum_256(sq, tmp);
    float rs = rsqrtf(sq * (1.0f / (float)(D_ - 1)));
    #pragma unroll
    for (int i = 0; i < 4; ++i) {
        float o = (vals[i] - m) * rs;
        outf[(size_t)row * D_ + tid + i*256] = o;
        if (outb) outb[(size_t)row * D_ + tid + i*256] = f2bf(o);
    }
}

// ---------------------------------------------------------------------------
extern "C" void kernel_launch(void* const* d_in, const int* in_sizes, int n_in,
                              void* d_out, int out_size, void* d_ws, size_t ws_size,
                              hipStream_t stream)
{
    const float* x  = (const float*)d_in[0];
    const float* Wq = (const float*)d_in[1];
    const float* Wk = (const float*)d_in[2];
    const float* Wv = (const float*)d_in[3];
    const float* Wo = (const float*)d_in[4];
    const float* W1 = (const float*)d_in[5];
    const float* b1 = (const float*)d_in[6];
    const float* W2 = (const float*)d_in[7];
    const float* b2 = (const float*)d_in[8];
    float* out = (float*)d_out;

    const size_t MB = (size_t)1 << 20;
    char* base = (char*)d_ws;
    // lifetimes:                                           [steps alive]
    ushort* qkv    = (ushort*)(base +   0*MB);  // 24MB     [QKV..PV]
    float*  oproj  = (float*) (base +   0*MB);  // 16MB     [Wo..norm1]   (reuses qkv)
    ushort* xb     = (ushort*)(base +  24*MB);  //  8MB     [cvt..QKV]
    ushort* hid    = (ushort*)(base +  24*MB);  // 32MB     [W1..W2]      (reuses xb/Wqkvt/vt/csum)
    ushort* Wqkvt  = (ushort*)(base +  32*MB);  //  6MB     [cvt..QKV]
    ushort* vt     = (ushort*)(base +  38*MB);  //  8MB     [vscale..PV]
    float*  csum   = (float*) (base +  46*MB);  // .25MB    [csum..vscale]
    ushort* Wot    = (ushort*)(base +  56*MB);  //  2MB     [cvt..Wo]
    ushort* W1t    = (ushort*)(base +  58*MB);  //  8MB     [cvt..W1]
    ushort* W2t    = (ushort*)(base +  66*MB);  //  8MB     [cvt..W2]
    ushort* attn_o = (ushort*)(base +  74*MB);  //  8MB     [PV..Wo]
    float*  out1f  = (float*) (base +  82*MB);  // 16MB     [norm1..W2]
    ushort* out1b  = (ushort*)(base +  98*MB);  //  8MB     [norm1..W1]
    float*  ffout  = (float*) (base + 106*MB);  // 16MB     [W2..norm2]
    // total 122MB

    // 1. converts / transposes
    cvt_bf16_kernel<<<dim3(BT_*D_/1024), 256, 0, stream>>>(x, xb, BT_*D_);
    transpose_bf16_kernel<<<dim3(2, 32, 16), 256, 0, stream>>>(
        Wq, Wqkvt + 0*1048576, 1024, 64, 65536, 65536);
    transpose_bf16_kernel<<<dim3(2, 32, 16), 256, 0, stream>>>(
        Wk, Wqkvt + 1*1048576, 1024, 64, 65536, 65536);
    transpose_bf16_kernel<<<dim3(2, 32, 16), 256, 0, stream>>>(
        Wv, Wqkvt + 2*1048576, 1024, 64, 65536, 65536);
    transpose_bf16_kernel<<<dim3(32, 32, 1), 256, 0, stream>>>(
        Wo, Wot, 1024, 1024, 0, 0);
    transpose_bf16_kernel<<<dim3(128, 32, 1), 256, 0, stream>>>(
        W1, W1t, 1024, 4096, 0, 0);
    transpose_bf16_kernel<<<dim3(32, 128, 1), 256, 0, stream>>>(
        W2, W2t, 4096, 1024, 0, 0);

    // 2. QKV: [4096,1024] @ [3072,1024]^T -> qkv bf16 [4096,3072]
    gemm_nt_kernel<1><<<dim3(3072/128, 4096/128), 256, 0, stream>>>(
        xb, 1024, Wqkvt, 1024, qkv, 3072, 1024, nullptr, nullptr, 0);
    // 3. column sums of exp(scores)
    csum_kernel<<<dim3(T_/128, B_*H_), 256, 0, stream>>>(qkv, csum);
    // 4. vt = (v/colsum)^T
    vscale_kernel<<<dim3(T_/64, B_*H_), 256, 0, stream>>>(qkv, csum, vt);
    // 5. PV
    attn_pv_kernel<<<dim3(T_/64, B_*H_), 256, 0, stream>>>(qkv, vt, attn_o);
    // 6. Wo projection + residual x -> oproj f32
    gemm_nt_kernel<0><<<dim3(1024/128, 4096/128), 256, 0, stream>>>(
        attn_o, 1024, Wot, 1024, oproj, 1024, 1024, nullptr, x, 0);
    // 7. norm1 -> out1f (f32) + out1b (bf16)
    norm_kernel<<<dim3(BT_), 256, 0, stream>>>(oproj, out1f, out1b);
    // 8. FFN up + ReLU -> hid bf16
    gemm_nt_kernel<1><<<dim3(4096/128, 4096/128), 256, 0, stream>>>(
        out1b, 1024, W1t, 1024, hid, 4096, 1024, b1, nullptr, 1);
    // 9. FFN down + bias + residual out1 -> ffout f32
    gemm_nt_kernel<0><<<dim3(1024/128, 4096/128), 256, 0, stream>>>(
        hid, 4096, W2t, 4096, ffout, 1024, 4096, b2, out1f, 0);
    // 10. norm2 -> out
    norm_kernel<<<dim3(BT_), 256, 0, stream>>>(ffout, out, nullptr);
}

// Round 3
// 516.010 us; speedup vs baseline: 4.8926x; 1.0128x over previous
//
#include <hip/hip_runtime.h>
#include <hip/hip_bf16.h>
#include <math.h>

#define B_  2
#define T_  2048
#define D_  1024
#define H_  16
#define DK_ 64
#define FF_ 4096
#define BT_ (B_*T_)

typedef __attribute__((ext_vector_type(8))) short bf16x8;
typedef __attribute__((ext_vector_type(4))) float f32x4;

__device__ __forceinline__ ushort f2bf(float f) {
    __hip_bfloat16 h = __float2bfloat16(f);
    return *reinterpret_cast<ushort*>(&h);
}
__device__ __forceinline__ float bf2f(ushort u) {
    __hip_bfloat16 h;
    *reinterpret_cast<ushort*>(&h) = u;
    return __bfloat162float(h);
}

// async global->LDS, 16B per lane. LDS dest must be wave-uniform base + lane*16.
__device__ __forceinline__ void g2l16(const ushort* g, ushort* l) {
    __builtin_amdgcn_global_load_lds(
        (const __attribute__((address_space(1))) void*)g,
        (__attribute__((address_space(3))) void*)l, 16, 0, 0);
}

// ---------------------------------------------------------------------------
// f32 -> bf16 elementwise (vectorized, n multiple of 1024)
// ---------------------------------------------------------------------------
__global__ __launch_bounds__(256) void cvt_bf16_kernel(
    const float* __restrict__ in, ushort* __restrict__ out, int n)
{
    int i = (blockIdx.x * 256 + threadIdx.x) * 4;
    if (i >= n) return;
    float4 v = *(const float4*)(in + i);
    ushort4 o;
    o.x = f2bf(v.x); o.y = f2bf(v.y); o.z = f2bf(v.z); o.w = f2bf(v.w);
    *(ushort4*)(out + i) = o;
}

// ---------------------------------------------------------------------------
// transpose + convert: in f32 [K][N] -> out bf16 [N][K]; batched over z.
// ---------------------------------------------------------------------------
__global__ __launch_bounds__(256) void transpose_bf16_kernel(
    const float* __restrict__ in, ushort* __restrict__ out,
    int K, int N, long in_bstride, long out_bstride)
{
    __shared__ float t[32][33];
    const float* ib = in + (size_t)blockIdx.z * in_bstride;
    ushort* ob = out + (size_t)blockIdx.z * out_bstride;
    int n0 = blockIdx.x * 32, k0 = blockIdx.y * 32;
    int tid = threadIdx.x;
    int r = tid >> 3, c4 = (tid & 7) * 4;
    float4 v = *(const float4*)(ib + (size_t)(k0 + r) * N + n0 + c4);
    t[r][c4] = v.x; t[r][c4+1] = v.y; t[r][c4+2] = v.z; t[r][c4+3] = v.w;
    __syncthreads();
    int n = tid >> 3, kc = (tid & 7) * 4;
    ushort4 o;
    o.x = f2bf(t[kc+0][n]); o.y = f2bf(t[kc+1][n]);
    o.z = f2bf(t[kc+2][n]); o.w = f2bf(t[kc+3][n]);
    *(ushort4*)(ob + (size_t)(n0 + n) * K + k0 + kc) = o;
}

// ---------------------------------------------------------------------------
// NT GEMM, bf16 MFMA: C[M][N] = A[M][K] @ Bt[N][K]^T  (+bias +resid +relu)
// 128x128 tile, BK=32, 256 threads (4 waves, 2x2 quadrants of 64x64).
// Staging via global_load_lds width=16 (m97 pattern): for each (wave, p),
// idx = w*64 + p*256 + l gives constant kc and consecutive m -> each wave
// writes one contiguous 1024B LDS span = wave-uniform base + lane*16.
// ---------------------------------------------------------------------------
template<int OUT_BF16>
__global__ __launch_bounds__(256) void gemm_nt_kernel(
    const ushort* __restrict__ A, int lda,
    const ushort* __restrict__ Bt, int ldb,
    void* __restrict__ C, int ldc, int K,
    const float* __restrict__ bias,
    const float* __restrict__ resid, int relu)
{
    __shared__ __attribute__((aligned(16))) ushort As[4][128][8];
    __shared__ __attribute__((aligned(16))) ushort Bs[4][128][8];
    int row0 = blockIdx.y * 128, col0 = blockIdx.x * 128;
    int tid = threadIdx.x;
    int w = tid >> 6, l = tid & 63;
    int wr = (w >> 1) * 64, wc = (w & 1) * 64;

    // per-thread staging coords (constant across K loop)
    int m0 = tid & 127, kc0 = tid >> 7;          // p = 0
    int m1 = (tid + 256) & 127, kc1 = (tid + 256) >> 7;  // p = 1
    const ushort* ga0 = A  + (size_t)(row0 + m0) * lda + kc0 * 8;
    const ushort* ga1 = A  + (size_t)(row0 + m1) * lda + kc1 * 8;
    const ushort* gb0 = Bt + (size_t)(col0 + m0) * ldb + kc0 * 8;
    const ushort* gb1 = Bt + (size_t)(col0 + m1) * ldb + kc1 * 8;
    ushort* la0 = &As[kc0][m0][0];
    ushort* la1 = &As[kc1][m1][0];
    ushort* lb0 = &Bs[kc0][m0][0];
    ushort* lb1 = &Bs[kc1][m1][0];

    f32x4 acc[4][4];
    #pragma unroll
    for (int i = 0; i < 4; ++i)
        #pragma unroll
        for (int j = 0; j < 4; ++j) acc[i][j] = (f32x4){0.f, 0.f, 0.f, 0.f};

    for (int k0 = 0; k0 < K; k0 += 32) {
        __syncthreads();                 // prior iter's ds_reads done
        g2l16(ga0 + k0, la0);
        g2l16(ga1 + k0, la1);
        g2l16(gb0 + k0, lb0);
        g2l16(gb1 + k0, lb1);
        __syncthreads();                 // vmcnt drained -> LDS valid
        int kc = l >> 4;
        bf16x8 af[4], bfr[4];
        #pragma unroll
        for (int i = 0; i < 4; ++i)
            af[i] = *(const bf16x8*)&As[kc][wr + i*16 + (l & 15)][0];
        #pragma unroll
        for (int j = 0; j < 4; ++j)
            bfr[j] = *(const bf16x8*)&Bs[kc][wc + j*16 + (l & 15)][0];
        #pragma unroll
        for (int i = 0; i < 4; ++i)
            #pragma unroll
            for (int j = 0; j < 4; ++j)
                acc[i][j] = __builtin_amdgcn_mfma_f32_16x16x32_bf16(
                    af[i], bfr[j], acc[i][j], 0, 0, 0);
    }

    #pragma unroll
    for (int i = 0; i < 4; ++i) {
        int rbase = row0 + wr + i*16 + (l >> 4) * 4;
        #pragma unroll
        for (int j = 0; j < 4; ++j) {
            int col = col0 + wc + j*16 + (l & 15);
            float bv = bias ? bias[col] : 0.f;
            #pragma unroll
            for (int r = 0; r < 4; ++r) {
                int row = rbase + r;
                float val = acc[i][j][r] + bv;
                if (resid) val += resid[(size_t)row * ldc + col];
                if (relu)  val = fmaxf(val, 0.f);
                if (OUT_BF16) ((ushort*)C)[(size_t)row * ldc + col] = f2bf(val);
                else          ((float*)C)[(size_t)row * ldc + col]  = val;
            }
        }
    }
}

// ---------------------------------------------------------------------------
// colsum[s] = sum_q exp(q·k/8).  grid (T/128, B*H), 256 thr.
// qkv packed [bt][3072]: q at col 0, k at 1024, v at 2048 (+h*64).
// ---------------------------------------------------------------------------
__global__ __launch_bounds__(256) void csum_kernel(
    const ushort* __restrict__ qkv, float* __restrict__ col_sum)
{
    int bh = blockIdx.y, b = bh >> 4, h = bh & 15;
    int s0 = blockIdx.x * 128;
    const ushort* qb = qkv + (size_t)b * T_ * 3072 + h * 64;
    const ushort* kb = qb + 1024;
    __shared__ __attribute__((aligned(16))) ushort Ks[8][128][8];
    __shared__ __attribute__((aligned(16))) ushort Qs[8][64][8];
    int tid = threadIdx.x, w = tid >> 6, l = tid & 63;
    int scol = w * 32;

    #pragma unroll
    for (int p = 0; p < 4; ++p) {
        int idx = tid + p * 256;
        int s = idx & 127, kc = idx >> 7;
        *(uint4*)&Ks[kc][s][0] =
            *(const uint4*)(kb + (size_t)(s0 + s) * 3072 + kc * 8);
    }
    float cs[2] = {0.f, 0.f};
    for (int qt = 0; qt < T_ / 64; ++qt) {
        __syncthreads();
        #pragma unroll
        for (int p = 0; p < 2; ++p) {
            int idx = tid + p * 256;
            int qq = idx & 63, kc = idx >> 6;
            *(uint4*)&Qs[kc][qq][0] =
                *(const uint4*)(qb + (size_t)(qt*64 + qq) * 3072 + kc * 8);
        }
        __syncthreads();
        bf16x8 af[4][2], bfr[2][2];
        #pragma unroll
        for (int qi = 0; qi < 4; ++qi)
            #pragma unroll
            for (int ks = 0; ks < 2; ++ks)
                af[qi][ks] = *(const bf16x8*)&Qs[ks*4 + (l>>4)][qi*16 + (l & 15)][0];
        #pragma unroll
        for (int sj = 0; sj < 2; ++sj)
            #pragma unroll
            for (int ks = 0; ks < 2; ++ks)
                bfr[sj][ks] = *(const bf16x8*)&Ks[ks*4 + (l>>4)][scol + sj*16 + (l & 15)][0];
        #pragma unroll
        for (int qi = 0; qi < 4; ++qi)
            #pragma unroll
            for (int sj = 0; sj < 2; ++sj) {
                f32x4 d = (f32x4){0.f, 0.f, 0.f, 0.f};
                #pragma unroll
                for (int ks = 0; ks < 2; ++ks)
                    d = __builtin_amdgcn_mfma_f32_16x16x32_bf16(
                        af[qi][ks], bfr[sj][ks], d, 0, 0, 0);
                cs[sj] += __expf(d[0]*0.125f) + __expf(d[1]*0.125f)
                        + __expf(d[2]*0.125f) + __expf(d[3]*0.125f);
            }
    }
    #pragma unroll
    for (int sj = 0; sj < 2; ++sj) {
        float v = cs[sj];
        v += __shfl_down(v, 32, 64);
        v += __shfl_down(v, 16, 64);
        if (l < 16)
            col_sum[(size_t)bh * T_ + s0 + scol + sj*16 + l] = v;
    }
}

// ---------------------------------------------------------------------------
// vt[bh][dv][s] = v[bh][s][dv] / colsum[bh][s]   (bf16, transposed V)
// grid (T/64, B*H), 256 thr.
// ---------------------------------------------------------------------------
__global__ __launch_bounds__(256) void vscale_kernel(
    const ushort* __restrict__ qkv, const float* __restrict__ col_sum,
    ushort* __restrict__ vt)
{
    int bh = blockIdx.y, b = bh >> 4, h = bh & 15;
    int s0 = blockIdx.x * 64;
    const ushort* vb = qkv + (size_t)b * T_ * 3072 + 2048 + h * 64;
    __shared__ float t[64][65];
    int tid = threadIdx.x;
    #pragma unroll
    for (int p = 0; p < 2; ++p) {
        int idx = tid + p * 256;
        int s = idx >> 3, c0 = (idx & 7) * 8;
        uint4 raw = *(const uint4*)(vb + (size_t)(s0 + s) * 3072 + c0);
        float rc = 1.0f / col_sum[(size_t)bh * T_ + s0 + s];
        ushort* u = (ushort*)&raw;
        #pragma unroll
        for (int i = 0; i < 8; ++i) t[s][c0 + i] = bf2f(u[i]) * rc;
    }
    __syncthreads();
    #pragma unroll
    for (int p = 0; p < 2; ++p) {
        int idx = tid + p * 256;
        int dv = idx >> 3, sc = (idx & 7) * 8;
        ushort o[8];
        #pragma unroll
        for (int i = 0; i < 8; ++i) o[i] = f2bf(t[sc + i][dv]);
        *(uint4*)(vt + ((size_t)bh * 64 + dv) * T_ + s0 + sc) = *(uint4*)o;
    }
}

// ---------------------------------------------------------------------------
// PV: O[q][dv] = sum_s exp(q·k/8) * vt[dv][s].  grid (T/64, B*H), 256 thr.
// Each wave owns 16 q-rows; E tile is wave-private in LDS (no extra barrier).
// ---------------------------------------------------------------------------
__global__ __launch_bounds__(256) void attn_pv_kernel(
    const ushort* __restrict__ qkv, const ushort* __restrict__ vt,
    ushort* __restrict__ attn_o)
{
    int bh = blockIdx.y, b = bh >> 4, h = bh & 15;
    int q0 = blockIdx.x * 64;
    const ushort* qb = qkv + (size_t)b * T_ * 3072 + h * 64;
    const ushort* kb = qb + 1024;
    const ushort* vtb = vt + (size_t)bh * 64 * T_;
    __shared__ __attribute__((aligned(16))) ushort Qs[8][64][8];
    __shared__ __attribute__((aligned(16))) ushort Ks[8][64][8];
    __shared__ __attribute__((aligned(16))) ushort Vs[8][64][8];
    __shared__ __attribute__((aligned(16))) ushort Es[8][64][8];
    int tid = threadIdx.x, w = tid >> 6, l = tid & 63;
    int qw = w * 16;

    #pragma unroll
    for (int p = 0; p < 2; ++p) {
        int idx = tid + p * 256;
        int qq = idx & 63, kc = idx >> 6;
        *(uint4*)&Qs[kc][qq][0] =
            *(const uint4*)(qb + (size_t)(q0 + qq) * 3072 + kc * 8);
    }
    __syncthreads();
    bf16x8 qf[2];
    #pragma unroll
    for (int ks = 0; ks < 2; ++ks)
        qf[ks] = *(const bf16x8*)&Qs[ks*4 + (l>>4)][qw + (l & 15)][0];

    f32x4 oacc[4];
    #pragma unroll
    for (int j = 0; j < 4; ++j) oacc[j] = (f32x4){0.f, 0.f, 0.f, 0.f};

    for (int st = 0; st < T_ / 64; ++st) {
        int s0 = st * 64;
        __syncthreads();
        #pragma unroll
        for (int p = 0; p < 2; ++p) {
            int idx = tid + p * 256;
            int rr = idx & 63, kc = idx >> 6;
            *(uint4*)&Ks[kc][rr][0] =
                *(const uint4*)(kb + (size_t)(s0 + rr) * 3072 + kc * 8);
            *(uint4*)&Vs[kc][rr][0] =
                *(const uint4*)(vtb + (size_t)rr * T_ + s0 + kc * 8);
        }
        __syncthreads();
        // QK^T -> exp -> Es (wave-private q rows)
        #pragma unroll
        for (int sj = 0; sj < 4; ++sj) {
            f32x4 d = (f32x4){0.f, 0.f, 0.f, 0.f};
            #pragma unroll
            for (int ks = 0; ks < 2; ++ks) {
                bf16x8 kf = *(const bf16x8*)&Ks[ks*4 + (l>>4)][sj*16 + (l & 15)][0];
                d = __builtin_amdgcn_mfma_f32_16x16x32_bf16(qf[ks], kf, d, 0, 0, 0);
            }
            #pragma unroll
            for (int r = 0; r < 4; ++r) {
                int qq = qw + (l>>4)*4 + r;
                int ss = sj*16 + (l & 15);
                Es[ss >> 3][qq][ss & 7] = f2bf(__expf(d[r] * 0.125f));
            }
        }
        // PV
        bf16x8 ef[2];
        #pragma unroll
        for (int ks = 0; ks < 2; ++ks)
            ef[ks] = *(const bf16x8*)&Es[ks*4 + (l>>4)][qw + (l & 15)][0];
        #pragma unroll
        for (int j = 0; j < 4; ++j)
            #pragma unroll
            for (int ks = 0; ks < 2; ++ks) {
                bf16x8 vf = *(const bf16x8*)&Vs[ks*4 + (l>>4)][j*16 + (l & 15)][0];
                oacc[j] = __builtin_amdgcn_mfma_f32_16x16x32_bf16(ef[ks], vf, oacc[j], 0, 0, 0);
            }
    }
    #pragma unroll
    for (int j = 0; j < 4; ++j)
        #pragma unroll
        for (int r = 0; r < 4; ++r) {
            int qq = q0 + qw + (l>>4)*4 + r;
            int dv = j*16 + (l & 15);
            attn_o[(size_t)(b*T_ + qq) * 1024 + h*64 + dv] = f2bf(oacc[j][r]);
        }
}

// ---------------------------------------------------------------------------
// mean/std norm (Bessel), optional bf16 side-output.
// ---------------------------------------------------------------------------
__device__ __forceinline__ float block_reduce_sum_256(float v, float* tmp)
{
    #pragma unroll
    for (int off = 32; off; off >>= 1) v += __shfl_down(v, off, 64);
    int lane = threadIdx.x & 63, w = threadIdx.x >> 6;
    __syncthreads();
    if (lane == 0) tmp[w] = v;
    __syncthreads();
    return tmp[0] + tmp[1] + tmp[2] + tmp[3];
}

__global__ __launch_bounds__(256) void norm_kernel(
    const float* __restrict__ in, float* __restrict__ outf,
    ushort* __restrict__ outb)
{
    __shared__ float tmp[4];
    int row = blockIdx.x;
    const float* r = in + (size_t)row * D_;
    int tid = threadIdx.x;
    float vals[4];
    #pragma unroll
    for (int i = 0; i < 4; ++i) vals[i] = r[tid + i*256];
    float s = vals[0] + vals[1] + vals[2] + vals[3];
    s = block_reduce_sum_256(s, tmp);
    float m = s * (1.0f / (float)D_);
    float sq = 0.f;
    #pragma unroll
    for (int i = 0; i < 4; ++i) { float c = vals[i] - m; sq += c * c; }
    sq = block_reduce_sum_256(sq, tmp);
    float rs = rsqrtf(sq * (1.0f / (float)(D_ - 1)));
    #pragma unroll
    for (int i = 0; i < 4; ++i) {
        float o = (vals[i] - m) * rs;
        outf[(size_t)row * D_ + tid + i*256] = o;
        if (outb) outb[(size_t)row * D_ + tid + i*256] = f2bf(o);
    }
}

// ---------------------------------------------------------------------------
extern "C" void kernel_launch(void* const* d_in, const int* in_sizes, int n_in,
                              void* d_out, int out_size, void* d_ws, size_t ws_size,
                              hipStream_t stream)
{
    const float* x  = (const float*)d_in[0];
    const float* Wq = (const float*)d_in[1];
    const float* Wk = (const float*)d_in[2];
    const float* Wv = (const float*)d_in[3];
    const float* Wo = (const float*)d_in[4];
    const float* W1 = (const float*)d_in[5];
    const float* b1 = (const float*)d_in[6];
    const float* W2 = (const float*)d_in[7];
    const float* b2 = (const float*)d_in[8];
    float* out = (float*)d_out;

    const size_t MB = (size_t)1 << 20;
    char* base = (char*)d_ws;
    // lifetimes:                                           [steps alive]
    ushort* qkv    = (ushort*)(base +   0*MB);  // 24MB     [QKV..PV]
    float*  oproj  = (float*) (base +   0*MB);  // 16MB     [Wo..norm1]   (reuses qkv)
    ushort* xb     = (ushort*)(base +  24*MB);  //  8MB     [cvt..QKV]
    ushort* hid    = (ushort*)(base +  24*MB);  // 32MB     [W1..W2]      (reuses xb/Wqkvt/vt/csum)
    ushort* Wqkvt  = (ushort*)(base +  32*MB);  //  6MB     [cvt..QKV]
    ushort* vt     = (ushort*)(base +  38*MB);  //  8MB     [vscale..PV]
    float*  csum   = (float*) (base +  46*MB);  // .25MB    [csum..vscale]
    ushort* Wot    = (ushort*)(base +  56*MB);  //  2MB     [cvt..Wo]
    ushort* W1t    = (ushort*)(base +  58*MB);  //  8MB     [cvt..W1]
    ushort* W2t    = (ushort*)(base +  66*MB);  //  8MB     [cvt..W2]
    ushort* attn_o = (ushort*)(base +  74*MB);  //  8MB     [PV..Wo]
    float*  out1f  = (float*) (base +  82*MB);  // 16MB     [norm1..W2]
    ushort* out1b  = (ushort*)(base +  98*MB);  //  8MB     [norm1..W1]
    float*  ffout  = (float*) (base + 106*MB);  // 16MB     [W2..norm2]
    // total 122MB

    // 1. converts / transposes
    cvt_bf16_kernel<<<dim3(BT_*D_/1024), 256, 0, stream>>>(x, xb, BT_*D_);
    transpose_bf16_kernel<<<dim3(2, 32, 16), 256, 0, stream>>>(
        Wq, Wqkvt + 0*1048576, 1024, 64, 65536, 65536);
    transpose_bf16_kernel<<<dim3(2, 32, 16), 256, 0, stream>>>(
        Wk, Wqkvt + 1*1048576, 1024, 64, 65536, 65536);
    transpose_bf16_kernel<<<dim3(2, 32, 16), 256, 0, stream>>>(
        Wv, Wqkvt + 2*1048576, 1024, 64, 65536, 65536);
    transpose_bf16_kernel<<<dim3(32, 32, 1), 256, 0, stream>>>(
        Wo, Wot, 1024, 1024, 0, 0);
    transpose_bf16_kernel<<<dim3(128, 32, 1), 256, 0, stream>>>(
        W1, W1t, 1024, 4096, 0, 0);
    transpose_bf16_kernel<<<dim3(32, 128, 1), 256, 0, stream>>>(
        W2, W2t, 4096, 1024, 0, 0);

    // 2. QKV: [4096,1024] @ [3072,1024]^T -> qkv bf16 [4096,3072]
    gemm_nt_kernel<1><<<dim3(3072/128, 4096/128), 256, 0, stream>>>(
        xb, 1024, Wqkvt, 1024, qkv, 3072, 1024, nullptr, nullptr, 0);
    // 3. column sums of exp(scores)
    csum_kernel<<<dim3(T_/128, B_*H_), 256, 0, stream>>>(qkv, csum);
    // 4. vt = (v/colsum)^T
    vscale_kernel<<<dim3(T_/64, B_*H_), 256, 0, stream>>>(qkv, csum, vt);
    // 5. PV
    attn_pv_kernel<<<dim3(T_/64, B_*H_), 256, 0, stream>>>(qkv, vt, attn_o);
    // 6. Wo projection + residual x -> oproj f32
    gemm_nt_kernel<0><<<dim3(1024/128, 4096/128), 256, 0, stream>>>(
        attn_o, 1024, Wot, 1024, oproj, 1024, 1024, nullptr, x, 0);
    // 7. norm1 -> out1f (f32) + out1b (bf16)
    norm_kernel<<<dim3(BT_), 256, 0, stream>>>(oproj, out1f, out1b);
    // 8. FFN up + ReLU -> hid bf16
    gemm_nt_kernel<1><<<dim3(4096/128, 4096/128), 256, 0, stream>>>(
        out1b, 1024, W1t, 1024, hid, 4096, 1024, b1, nullptr, 1);
    // 9. FFN down + bias + residual out1 -> ffout f32
    gemm_nt_kernel<0><<<dim3(1024/128, 4096/128), 256, 0, stream>>>(
        hid, 4096, W2t, 4096, ffout, 1024, 4096, b2, out1f, 0);
    // 10. norm2 -> out
    norm_kernel<<<dim3(BT_), 256, 0, stream>>>(ffout, out, nullptr);
}

// Round 4
// 503.011 us; speedup vs baseline: 5.0191x; 1.0258x over previous
//
#include <hip/hip_runtime.h>
#include <hip/hip_bf16.h>
#include <math.h>

#define B_  2
#define T_  2048
#define D_  1024
#define H_  16
#define DK_ 64
#define FF_ 4096
#define BT_ (B_*T_)

typedef __attribute__((ext_vector_type(8))) short bf16x8;
typedef __attribute__((ext_vector_type(4))) float f32x4;

__device__ __forceinline__ ushort f2bf(float f) {
    __hip_bfloat16 h = __float2bfloat16(f);
    return *reinterpret_cast<ushort*>(&h);
}
__device__ __forceinline__ float bf2f(ushort u) {
    __hip_bfloat16 h;
    *reinterpret_cast<ushort*>(&h) = u;
    return __bfloat162float(h);
}

// async global->LDS, 16B per lane. LDS dest must be wave-uniform base + lane*16.
__device__ __forceinline__ void g2l16(const ushort* g, ushort* l) {
    __builtin_amdgcn_global_load_lds(
        (const __attribute__((address_space(1))) void*)g,
        (__attribute__((address_space(3))) void*)l, 16, 0, 0);
}

// ---------------------------------------------------------------------------
// f32 -> bf16 elementwise (vectorized, n multiple of 1024)
// ---------------------------------------------------------------------------
__global__ __launch_bounds__(256) void cvt_bf16_kernel(
    const float* __restrict__ in, ushort* __restrict__ out, int n)
{
    int i = (blockIdx.x * 256 + threadIdx.x) * 4;
    if (i >= n) return;
    float4 v = *(const float4*)(in + i);
    ushort4 o;
    o.x = f2bf(v.x); o.y = f2bf(v.y); o.z = f2bf(v.z); o.w = f2bf(v.w);
    *(ushort4*)(out + i) = o;
}

// ---------------------------------------------------------------------------
// transpose + convert: in f32 [K][N] -> out bf16 [N][K]; batched over z.
// ---------------------------------------------------------------------------
__global__ __launch_bounds__(256) void transpose_bf16_kernel(
    const float* __restrict__ in, ushort* __restrict__ out,
    int K, int N, long in_bstride, long out_bstride)
{
    __shared__ float t[32][33];
    const float* ib = in + (size_t)blockIdx.z * in_bstride;
    ushort* ob = out + (size_t)blockIdx.z * out_bstride;
    int n0 = blockIdx.x * 32, k0 = blockIdx.y * 32;
    int tid = threadIdx.x;
    int r = tid >> 3, c4 = (tid & 7) * 4;
    float4 v = *(const float4*)(ib + (size_t)(k0 + r) * N + n0 + c4);
    t[r][c4] = v.x; t[r][c4+1] = v.y; t[r][c4+2] = v.z; t[r][c4+3] = v.w;
    __syncthreads();
    int n = tid >> 3, kc = (tid & 7) * 4;
    ushort4 o;
    o.x = f2bf(t[kc+0][n]); o.y = f2bf(t[kc+1][n]);
    o.z = f2bf(t[kc+2][n]); o.w = f2bf(t[kc+3][n]);
    *(ushort4*)(ob + (size_t)(n0 + n) * K + k0 + kc) = o;
}

// ---------------------------------------------------------------------------
// NT GEMM, bf16 MFMA: C[M][N] = A[M][K] @ Bt[N][K]^T  (+bias +resid +relu)
// 128x128 tile, BK=32, 256 threads (4 waves, 2x2 quadrants of 64x64).
// Double-buffered LDS, 1 barrier per K-tile: prefetch tile t+1 via
// global_load_lds while tile t computes; __syncthreads() (vmcnt+lgkm drain)
// publishes the prefetch and protects the WAR on buf^1.
// XCD-aware swizzle: blocks sharing an A-panel land on the same XCD's L2.
// ---------------------------------------------------------------------------
template<int OUT_BF16>
__global__ __launch_bounds__(256) void gemm_nt_kernel(
    const ushort* __restrict__ A, int lda,
    const ushort* __restrict__ Bt, int ldb,
    void* __restrict__ C, int ldc, int K,
    const float* __restrict__ bias,
    const float* __restrict__ resid, int relu)
{
    __shared__ __attribute__((aligned(16))) ushort As[2][4][128][8];
    __shared__ __attribute__((aligned(16))) ushort Bs[2][4][128][8];

    // XCD swizzle (requires nwg % 8 == 0 -- true for all launches here)
    int nwg  = gridDim.x * gridDim.y;
    int orig = blockIdx.y * gridDim.x + blockIdx.x;
    int work = (orig & 7) * (nwg >> 3) + (orig >> 3);
    int bx = work % gridDim.x, by = work / gridDim.x;

    int row0 = by * 128, col0 = bx * 128;
    int tid = threadIdx.x;
    int w = tid >> 6, l = tid & 63;
    int wr = (w >> 1) * 64, wc = (w & 1) * 64;

    // per-thread staging coords (constant across K loop); each (wave,p) pair
    // covers one contiguous 1024B LDS span = wave-uniform base + lane*16.
    int m0 = tid & 127, kc0 = tid >> 7;
    int m1 = (tid + 256) & 127, kc1 = (tid + 256) >> 7;
    const ushort* ga0 = A  + (size_t)(row0 + m0) * lda + kc0 * 8;
    const ushort* ga1 = A  + (size_t)(row0 + m1) * lda + kc1 * 8;
    const ushort* gb0 = Bt + (size_t)(col0 + m0) * ldb + kc0 * 8;
    const ushort* gb1 = Bt + (size_t)(col0 + m1) * ldb + kc1 * 8;

    f32x4 acc[4][4];
    #pragma unroll
    for (int i = 0; i < 4; ++i)
        #pragma unroll
        for (int j = 0; j < 4; ++j) acc[i][j] = (f32x4){0.f, 0.f, 0.f, 0.f};

    const int NT = K >> 5;
    // prologue: stage tile 0 into buf 0
    g2l16(ga0, &As[0][kc0][m0][0]);
    g2l16(ga1, &As[0][kc1][m1][0]);
    g2l16(gb0, &Bs[0][kc0][m0][0]);
    g2l16(gb1, &Bs[0][kc1][m1][0]);
    __syncthreads();

    int cur = 0;
    for (int t = 0; t < NT; ++t) {
        if (t + 1 < NT) {               // prefetch next tile into buf^1
            int k0 = (t + 1) << 5;
            g2l16(ga0 + k0, &As[cur ^ 1][kc0][m0][0]);
            g2l16(ga1 + k0, &As[cur ^ 1][kc1][m1][0]);
            g2l16(gb0 + k0, &Bs[cur ^ 1][kc0][m0][0]);
            g2l16(gb1 + k0, &Bs[cur ^ 1][kc1][m1][0]);
        }
        int kc = l >> 4;
        bf16x8 af[4], bfr[4];
        #pragma unroll
        for (int i = 0; i < 4; ++i)
            af[i] = *(const bf16x8*)&As[cur][kc][wr + i*16 + (l & 15)][0];
        #pragma unroll
        for (int j = 0; j < 4; ++j)
            bfr[j] = *(const bf16x8*)&Bs[cur][kc][wc + j*16 + (l & 15)][0];
        #pragma unroll
        for (int i = 0; i < 4; ++i)
            #pragma unroll
            for (int j = 0; j < 4; ++j)
                acc[i][j] = __builtin_amdgcn_mfma_f32_16x16x32_bf16(
                    af[i], bfr[j], acc[i][j], 0, 0, 0);
        __syncthreads();                // publishes prefetch, protects WAR
        cur ^= 1;
    }

    #pragma unroll
    for (int i = 0; i < 4; ++i) {
        int rbase = row0 + wr + i*16 + (l >> 4) * 4;
        #pragma unroll
        for (int j = 0; j < 4; ++j) {
            int col = col0 + wc + j*16 + (l & 15);
            float bv = bias ? bias[col] : 0.f;
            #pragma unroll
            for (int r = 0; r < 4; ++r) {
                int row = rbase + r;
                float val = acc[i][j][r] + bv;
                if (resid) val += resid[(size_t)row * ldc + col];
                if (relu)  val = fmaxf(val, 0.f);
                if (OUT_BF16) ((ushort*)C)[(size_t)row * ldc + col] = f2bf(val);
                else          ((float*)C)[(size_t)row * ldc + col]  = val;
            }
        }
    }
}

// ---------------------------------------------------------------------------
// colsum[s] = sum_q exp(q·k/8).  grid (T/128, B*H), 256 thr.
// qkv packed [bt][3072]: q at col 0, k at 1024, v at 2048 (+h*64).
// ---------------------------------------------------------------------------
__global__ __launch_bounds__(256) void csum_kernel(
    const ushort* __restrict__ qkv, float* __restrict__ col_sum)
{
    int bh = blockIdx.y, b = bh >> 4, h = bh & 15;
    int s0 = blockIdx.x * 128;
    const ushort* qb = qkv + (size_t)b * T_ * 3072 + h * 64;
    const ushort* kb = qb + 1024;
    __shared__ __attribute__((aligned(16))) ushort Ks[8][128][8];
    __shared__ __attribute__((aligned(16))) ushort Qs[8][64][8];
    int tid = threadIdx.x, w = tid >> 6, l = tid & 63;
    int scol = w * 32;

    #pragma unroll
    for (int p = 0; p < 4; ++p) {
        int idx = tid + p * 256;
        int s = idx & 127, kc = idx >> 7;
        *(uint4*)&Ks[kc][s][0] =
            *(const uint4*)(kb + (size_t)(s0 + s) * 3072 + kc * 8);
    }
    float cs[2] = {0.f, 0.f};
    for (int qt = 0; qt < T_ / 64; ++qt) {
        __syncthreads();
        #pragma unroll
        for (int p = 0; p < 2; ++p) {
            int idx = tid + p * 256;
            int qq = idx & 63, kc = idx >> 6;
            *(uint4*)&Qs[kc][qq][0] =
                *(const uint4*)(qb + (size_t)(qt*64 + qq) * 3072 + kc * 8);
        }
        __syncthreads();
        bf16x8 af[4][2], bfr[2][2];
        #pragma unroll
        for (int qi = 0; qi < 4; ++qi)
            #pragma unroll
            for (int ks = 0; ks < 2; ++ks)
                af[qi][ks] = *(const bf16x8*)&Qs[ks*4 + (l>>4)][qi*16 + (l & 15)][0];
        #pragma unroll
        for (int sj = 0; sj < 2; ++sj)
            #pragma unroll
            for (int ks = 0; ks < 2; ++ks)
                bfr[sj][ks] = *(const bf16x8*)&Ks[ks*4 + (l>>4)][scol + sj*16 + (l & 15)][0];
        #pragma unroll
        for (int qi = 0; qi < 4; ++qi)
            #pragma unroll
            for (int sj = 0; sj < 2; ++sj) {
                f32x4 d = (f32x4){0.f, 0.f, 0.f, 0.f};
                #pragma unroll
                for (int ks = 0; ks < 2; ++ks)
                    d = __builtin_amdgcn_mfma_f32_16x16x32_bf16(
                        af[qi][ks], bfr[sj][ks], d, 0, 0, 0);
                cs[sj] += __expf(d[0]*0.125f) + __expf(d[1]*0.125f)
                        + __expf(d[2]*0.125f) + __expf(d[3]*0.125f);
            }
    }
    #pragma unroll
    for (int sj = 0; sj < 2; ++sj) {
        float v = cs[sj];
        v += __shfl_down(v, 32, 64);
        v += __shfl_down(v, 16, 64);
        if (l < 16)
            col_sum[(size_t)bh * T_ + s0 + scol + sj*16 + l] = v;
    }
}

// ---------------------------------------------------------------------------
// vt[bh][dv][s] = v[bh][s][dv] / colsum[bh][s]   (bf16, transposed V)
// grid (T/64, B*H), 256 thr.
// ---------------------------------------------------------------------------
__global__ __launch_bounds__(256) void vscale_kernel(
    const ushort* __restrict__ qkv, const float* __restrict__ col_sum,
    ushort* __restrict__ vt)
{
    int bh = blockIdx.y, b = bh >> 4, h = bh & 15;
    int s0 = blockIdx.x * 64;
    const ushort* vb = qkv + (size_t)b * T_ * 3072 + 2048 + h * 64;
    __shared__ float t[64][65];
    int tid = threadIdx.x;
    #pragma unroll
    for (int p = 0; p < 2; ++p) {
        int idx = tid + p * 256;
        int s = idx >> 3, c0 = (idx & 7) * 8;
        uint4 raw = *(const uint4*)(vb + (size_t)(s0 + s) * 3072 + c0);
        float rc = 1.0f / col_sum[(size_t)bh * T_ + s0 + s];
        ushort* u = (ushort*)&raw;
        #pragma unroll
        for (int i = 0; i < 8; ++i) t[s][c0 + i] = bf2f(u[i]) * rc;
    }
    __syncthreads();
    #pragma unroll
    for (int p = 0; p < 2; ++p) {
        int idx = tid + p * 256;
        int dv = idx >> 3, sc = (idx & 7) * 8;
        ushort o[8];
        #pragma unroll
        for (int i = 0; i < 8; ++i) o[i] = f2bf(t[sc + i][dv]);
        *(uint4*)(vt + ((size_t)bh * 64 + dv) * T_ + s0 + sc) = *(uint4*)o;
    }
}

// ---------------------------------------------------------------------------
// PV: O[q][dv] = sum_s exp(q·k/8) * vt[dv][s].  grid (T/64, B*H), 256 thr.
// Each wave owns 16 q-rows; E tile is wave-private in LDS (no extra barrier).
// ---------------------------------------------------------------------------
__global__ __launch_bounds__(256) void attn_pv_kernel(
    const ushort* __restrict__ qkv, const ushort* __restrict__ vt,
    ushort* __restrict__ attn_o)
{
    int bh = blockIdx.y, b = bh >> 4, h = bh & 15;
    int q0 = blockIdx.x * 64;
    const ushort* qb = qkv + (size_t)b * T_ * 3072 + h * 64;
    const ushort* kb = qb + 1024;
    const ushort* vtb = vt + (size_t)bh * 64 * T_;
    __shared__ __attribute__((aligned(16))) ushort Qs[8][64][8];
    __shared__ __attribute__((aligned(16))) ushort Ks[8][64][8];
    __shared__ __attribute__((aligned(16))) ushort Vs[8][64][8];
    __shared__ __attribute__((aligned(16))) ushort Es[8][64][8];
    int tid = threadIdx.x, w = tid >> 6, l = tid & 63;
    int qw = w * 16;

    #pragma unroll
    for (int p = 0; p < 2; ++p) {
        int idx = tid + p * 256;
        int qq = idx & 63, kc = idx >> 6;
        *(uint4*)&Qs[kc][qq][0] =
            *(const uint4*)(qb + (size_t)(q0 + qq) * 3072 + kc * 8);
    }
    __syncthreads();
    bf16x8 qf[2];
    #pragma unroll
    for (int ks = 0; ks < 2; ++ks)
        qf[ks] = *(const bf16x8*)&Qs[ks*4 + (l>>4)][qw + (l & 15)][0];

    f32x4 oacc[4];
    #pragma unroll
    for (int j = 0; j < 4; ++j) oacc[j] = (f32x4){0.f, 0.f, 0.f, 0.f};

    for (int st = 0; st < T_ / 64; ++st) {
        int s0 = st * 64;
        __syncthreads();
        #pragma unroll
        for (int p = 0; p < 2; ++p) {
            int idx = tid + p * 256;
            int rr = idx & 63, kc = idx >> 6;
            *(uint4*)&Ks[kc][rr][0] =
                *(const uint4*)(kb + (size_t)(s0 + rr) * 3072 + kc * 8);
            *(uint4*)&Vs[kc][rr][0] =
                *(const uint4*)(vtb + (size_t)rr * T_ + s0 + kc * 8);
        }
        __syncthreads();
        // QK^T -> exp -> Es (wave-private q rows)
        #pragma unroll
        for (int sj = 0; sj < 4; ++sj) {
            f32x4 d = (f32x4){0.f, 0.f, 0.f, 0.f};
            #pragma unroll
            for (int ks = 0; ks < 2; ++ks) {
                bf16x8 kf = *(const bf16x8*)&Ks[ks*4 + (l>>4)][sj*16 + (l & 15)][0];
                d = __builtin_amdgcn_mfma_f32_16x16x32_bf16(qf[ks], kf, d, 0, 0, 0);
            }
            #pragma unroll
            for (int r = 0; r < 4; ++r) {
                int qq = qw + (l>>4)*4 + r;
                int ss = sj*16 + (l & 15);
                Es[ss >> 3][qq][ss & 7] = f2bf(__expf(d[r] * 0.125f));
            }
        }
        // PV
        bf16x8 ef[2];
        #pragma unroll
        for (int ks = 0; ks < 2; ++ks)
            ef[ks] = *(const bf16x8*)&Es[ks*4 + (l>>4)][qw + (l & 15)][0];
        #pragma unroll
        for (int j = 0; j < 4; ++j)
            #pragma unroll
            for (int ks = 0; ks < 2; ++ks) {
                bf16x8 vf = *(const bf16x8*)&Vs[ks*4 + (l>>4)][j*16 + (l & 15)][0];
                oacc[j] = __builtin_amdgcn_mfma_f32_16x16x32_bf16(ef[ks], vf, oacc[j], 0, 0, 0);
            }
    }
    #pragma unroll
    for (int j = 0; j < 4; ++j)
        #pragma unroll
        for (int r = 0; r < 4; ++r) {
            int qq = q0 + qw + (l>>4)*4 + r;
            int dv = j*16 + (l & 15);
            attn_o[(size_t)(b*T_ + qq) * 1024 + h*64 + dv] = f2bf(oacc[j][r]);
        }
}

// ---------------------------------------------------------------------------
// mean/std norm (Bessel), optional bf16 side-output.
// ---------------------------------------------------------------------------
__device__ __forceinline__ float block_reduce_sum_256(float v, float* tmp)
{
    #pragma unroll
    for (int off = 32; off; off >>= 1) v += __shfl_down(v, off, 64);
    int lane = threadIdx.x & 63, w = threadIdx.x >> 6;
    __syncthreads();
    if (lane == 0) tmp[w] = v;
    __syncthreads();
    return tmp[0] + tmp[1] + tmp[2] + tmp[3];
}

__global__ __launch_bounds__(256) void norm_kernel(
    const float* __restrict__ in, float* __restrict__ outf,
    ushort* __restrict__ outb)
{
    __shared__ float tmp[4];
    int row = blockIdx.x;
    const float* r = in + (size_t)row * D_;
    int tid = threadIdx.x;
    float vals[4];
    #pragma unroll
    for (int i = 0; i < 4; ++i) vals[i] = r[tid + i*256];
    float s = vals[0] + vals[1] + vals[2] + vals[3];
    s = block_reduce_sum_256(s, tmp);
    float m = s * (1.0f / (float)D_);
    float sq = 0.f;
    #pragma unroll
    for (int i = 0; i < 4; ++i) { float c = vals[i] - m; sq += c * c; }
    sq = block_reduce_sum_256(sq, tmp);
    float rs = rsqrtf(sq * (1.0f / (float)(D_ - 1)));
    #pragma unroll
    for (int i = 0; i < 4; ++i) {
        float o = (vals[i] - m) * rs;
        outf[(size_t)row * D_ + tid + i*256] = o;
        if (outb) outb[(size_t)row * D_ + tid + i*256] = f2bf(o);
    }
}

// ---------------------------------------------------------------------------
extern "C" void kernel_launch(void* const* d_in, const int* in_sizes, int n_in,
                              void* d_out, int out_size, void* d_ws, size_t ws_size,
                              hipStream_t stream)
{
    const float* x  = (const float*)d_in[0];
    const float* Wq = (const float*)d_in[1];
    const float* Wk = (const float*)d_in[2];
    const float* Wv = (const float*)d_in[3];
    const float* Wo = (const float*)d_in[4];
    const float* W1 = (const float*)d_in[5];
    const float* b1 = (const float*)d_in[6];
    const float* W2 = (const float*)d_in[7];
    const float* b2 = (const float*)d_in[8];
    float* out = (float*)d_out;

    const size_t MB = (size_t)1 << 20;
    char* base = (char*)d_ws;
    // lifetimes:                                           [steps alive]
    ushort* qkv    = (ushort*)(base +   0*MB);  // 24MB     [QKV..PV]
    float*  oproj  = (float*) (base +   0*MB);  // 16MB     [Wo..norm1]   (reuses qkv)
    ushort* xb     = (ushort*)(base +  24*MB);  //  8MB     [cvt..QKV]
    ushort* hid    = (ushort*)(base +  24*MB);  // 32MB     [W1..W2]      (reuses xb/Wqkvt/vt/csum)
    ushort* Wqkvt  = (ushort*)(base +  32*MB);  //  6MB     [cvt..QKV]
    ushort* vt     = (ushort*)(base +  38*MB);  //  8MB     [vscale..PV]
    float*  csum   = (float*) (base +  46*MB);  // .25MB    [csum..vscale]
    ushort* Wot    = (ushort*)(base +  56*MB);  //  2MB     [cvt..Wo]
    ushort* W1t    = (ushort*)(base +  58*MB);  //  8MB     [cvt..W1]
    ushort* W2t    = (ushort*)(base +  66*MB);  //  8MB     [cvt..W2]
    ushort* attn_o = (ushort*)(base +  74*MB);  //  8MB     [PV..Wo]
    float*  out1f  = (float*) (base +  82*MB);  // 16MB     [norm1..W2]
    ushort* out1b  = (ushort*)(base +  98*MB);  //  8MB     [norm1..W1]
    float*  ffout  = (float*) (base + 106*MB);  // 16MB     [W2..norm2]
    // total 122MB

    // 1. converts / transposes
    cvt_bf16_kernel<<<dim3(BT_*D_/1024), 256, 0, stream>>>(x, xb, BT_*D_);
    transpose_bf16_kernel<<<dim3(2, 32, 16), 256, 0, stream>>>(
        Wq, Wqkvt + 0*1048576, 1024, 64, 65536, 65536);
    transpose_bf16_kernel<<<dim3(2, 32, 16), 256, 0, stream>>>(
        Wk, Wqkvt + 1*1048576, 1024, 64, 65536, 65536);
    transpose_bf16_kernel<<<dim3(2, 32, 16), 256, 0, stream>>>(
        Wv, Wqkvt + 2*1048576, 1024, 64, 65536, 65536);
    transpose_bf16_kernel<<<dim3(32, 32, 1), 256, 0, stream>>>(
        Wo, Wot, 1024, 1024, 0, 0);
    transpose_bf16_kernel<<<dim3(128, 32, 1), 256, 0, stream>>>(
        W1, W1t, 1024, 4096, 0, 0);
    transpose_bf16_kernel<<<dim3(32, 128, 1), 256, 0, stream>>>(
        W2, W2t, 4096, 1024, 0, 0);

    // 2. QKV: [4096,1024] @ [3072,1024]^T -> qkv bf16 [4096,3072]
    gemm_nt_kernel<1><<<dim3(3072/128, 4096/128), 256, 0, stream>>>(
        xb, 1024, Wqkvt, 1024, qkv, 3072, 1024, nullptr, nullptr, 0);
    // 3. column sums of exp(scores)
    csum_kernel<<<dim3(T_/128, B_*H_), 256, 0, stream>>>(qkv, csum);
    // 4. vt = (v/colsum)^T
    vscale_kernel<<<dim3(T_/64, B_*H_), 256, 0, stream>>>(qkv, csum, vt);
    // 5. PV
    attn_pv_kernel<<<dim3(T_/64, B_*H_), 256, 0, stream>>>(qkv, vt, attn_o);
    // 6. Wo projection + residual x -> oproj f32
    gemm_nt_kernel<0><<<dim3(1024/128, 4096/128), 256, 0, stream>>>(
        attn_o, 1024, Wot, 1024, oproj, 1024, 1024, nullptr, x, 0);
    // 7. norm1 -> out1f (f32) + out1b (bf16)
    norm_kernel<<<dim3(BT_), 256, 0, stream>>>(oproj, out1f, out1b);
    // 8. FFN up + ReLU -> hid bf16
    gemm_nt_kernel<1><<<dim3(4096/128, 4096/128), 256, 0, stream>>>(
        out1b, 1024, W1t, 1024, hid, 4096, 1024, b1, nullptr, 1);
    // 9. FFN down + bias + residual out1 -> ffout f32
    gemm_nt_kernel<0><<<dim3(1024/128, 4096/128), 256, 0, stream>>>(
        hid, 4096, W2t, 4096, ffout, 1024, 4096, b2, out1f, 0);
    // 10. norm2 -> out
    norm_kernel<<<dim3(BT_), 256, 0, stream>>>(ffout, out, nullptr);
}

// Round 5
// 476.305 us; speedup vs baseline: 5.3005x; 1.0561x over previous
//
#include <hip/hip_runtime.h>
#include <hip/hip_bf16.h>
#include <math.h>

#define B_  2
#define T_  2048
#define D_  1024
#define H_  16
#define DK_ 64
#define FF_ 4096
#define BT_ (B_*T_)

typedef __attribute__((ext_vector_type(8))) short bf16x8;
typedef __attribute__((ext_vector_type(4))) float f32x4;

__device__ __forceinline__ ushort f2bf(float f) {
    __hip_bfloat16 h = __float2bfloat16(f);
    return *reinterpret_cast<ushort*>(&h);
}
__device__ __forceinline__ float bf2f(ushort u) {
    __hip_bfloat16 h;
    *reinterpret_cast<ushort*>(&h) = u;
    return __bfloat162float(h);
}

// async global->LDS, 16B per lane. LDS dest must be wave-uniform base + lane*16.
__device__ __forceinline__ void g2l16(const ushort* g, ushort* l) {
    __builtin_amdgcn_global_load_lds(
        (const __attribute__((address_space(1))) void*)g,
        (__attribute__((address_space(3))) void*)l, 16, 0, 0);
}

// ---------------------------------------------------------------------------
// f32 -> bf16 elementwise (vectorized, n multiple of 1024)
// ---------------------------------------------------------------------------
__global__ __launch_bounds__(256) void cvt_bf16_kernel(
    const float* __restrict__ in, ushort* __restrict__ out, int n)
{
    int i = (blockIdx.x * 256 + threadIdx.x) * 4;
    if (i >= n) return;
    float4 v = *(const float4*)(in + i);
    ushort4 o;
    o.x = f2bf(v.x); o.y = f2bf(v.y); o.z = f2bf(v.z); o.w = f2bf(v.w);
    *(ushort4*)(out + i) = o;
}

// ---------------------------------------------------------------------------
// transpose + convert: in f32 [K][N] -> out bf16 [N][K]; batched over z.
// ---------------------------------------------------------------------------
__global__ __launch_bounds__(256) void transpose_bf16_kernel(
    const float* __restrict__ in, ushort* __restrict__ out,
    int K, int N, long in_bstride, long out_bstride)
{
    __shared__ float t[32][33];
    const float* ib = in + (size_t)blockIdx.z * in_bstride;
    ushort* ob = out + (size_t)blockIdx.z * out_bstride;
    int n0 = blockIdx.x * 32, k0 = blockIdx.y * 32;
    int tid = threadIdx.x;
    int r = tid >> 3, c4 = (tid & 7) * 4;
    float4 v = *(const float4*)(ib + (size_t)(k0 + r) * N + n0 + c4);
    t[r][c4] = v.x; t[r][c4+1] = v.y; t[r][c4+2] = v.z; t[r][c4+3] = v.w;
    __syncthreads();
    int n = tid >> 3, kc = (tid & 7) * 4;
    ushort4 o;
    o.x = f2bf(t[kc+0][n]); o.y = f2bf(t[kc+1][n]);
    o.z = f2bf(t[kc+2][n]); o.w = f2bf(t[kc+3][n]);
    *(ushort4*)(ob + (size_t)(n0 + n) * K + k0 + kc) = o;
}

// ---------------------------------------------------------------------------
// 256x256-tile NT GEMM, bf16 MFMA, BK=64, 512 threads (8 waves, 2Mx4N,
// per-wave 128x64 output). Double-buffered 128KiB LDS, one barrier per
// K-tile, global_load_lds staging, XCD swizzle. Optional split-K via
// blockIdx.z (aZoff/bZoff/cZoff in elements).
// ---------------------------------------------------------------------------
template<int OUT_BF16>
__global__ __launch_bounds__(512) void gemm256_kernel(
    const ushort* __restrict__ A, int lda,
    const ushort* __restrict__ Bt, int ldb,
    void* __restrict__ C, int ldc, int K,
    const float* __restrict__ bias,
    const float* __restrict__ resid, int relu,
    long aZoff, long bZoff, long cZoff)
{
    __shared__ __attribute__((aligned(16))) ushort As[2][8][256][8];
    __shared__ __attribute__((aligned(16))) ushort Bs[2][8][256][8];

    A  += (size_t)blockIdx.z * aZoff;
    Bt += (size_t)blockIdx.z * bZoff;
    char* Cb = (char*)C + (size_t)blockIdx.z * cZoff * (OUT_BF16 ? 2 : 4);

    // XCD swizzle over x,y (nwg per z-slice must be %8==0 -- true here)
    int nwg  = gridDim.x * gridDim.y;
    int orig = blockIdx.y * gridDim.x + blockIdx.x;
    int work = (orig & 7) * (nwg >> 3) + (orig >> 3);
    int bx = work % gridDim.x, by = work / gridDim.x;

    int row0 = by * 256, col0 = bx * 256;
    int tid = threadIdx.x;
    int l = tid & 63;
    int w = tid >> 6;
    int wr = (w >> 2) * 128, wc = (w & 3) * 64;

    // staging coords: m const per thread, kc = kc0 + 2p
    int m = tid & 255, kc0 = tid >> 8;
    const ushort* gA = A  + (size_t)(row0 + m) * lda + kc0 * 8;
    const ushort* gB = Bt + (size_t)(col0 + m) * ldb + kc0 * 8;

    f32x4 acc[8][4];
    #pragma unroll
    for (int i = 0; i < 8; ++i)
        #pragma unroll
        for (int j = 0; j < 4; ++j) acc[i][j] = (f32x4){0.f, 0.f, 0.f, 0.f};

    const int NT = K >> 6;

    // prologue: stage tile 0 into buf 0
    #pragma unroll
    for (int p = 0; p < 4; ++p) {
        g2l16(gA + p*16, &As[0][kc0 + 2*p][m][0]);
        g2l16(gB + p*16, &Bs[0][kc0 + 2*p][m][0]);
    }
    __syncthreads();

    int cur = 0;
    for (int t = 0; t < NT; ++t) {
        if (t + 1 < NT) {
            int k0 = (t + 1) << 6;
            #pragma unroll
            for (int p = 0; p < 4; ++p) {
                g2l16(gA + k0 + p*16, &As[cur ^ 1][kc0 + 2*p][m][0]);
                g2l16(gB + k0 + p*16, &Bs[cur ^ 1][kc0 + 2*p][m][0]);
            }
        }
        #pragma unroll
        for (int ks = 0; ks < 2; ++ks) {
            bf16x8 bfr[4];
            #pragma unroll
            for (int j = 0; j < 4; ++j)
                bfr[j] = *(const bf16x8*)&Bs[cur][ks*4 + (l>>4)][wc + j*16 + (l & 15)][0];
            #pragma unroll
            for (int i = 0; i < 8; ++i) {
                bf16x8 a = *(const bf16x8*)&As[cur][ks*4 + (l>>4)][wr + i*16 + (l & 15)][0];
                #pragma unroll
                for (int j = 0; j < 4; ++j)
                    acc[i][j] = __builtin_amdgcn_mfma_f32_16x16x32_bf16(
                        a, bfr[j], acc[i][j], 0, 0, 0);
            }
        }
        __syncthreads();            // publishes prefetch, protects WAR
        cur ^= 1;
    }

    #pragma unroll
    for (int i = 0; i < 8; ++i) {
        int rbase = row0 + wr + i*16 + (l >> 4) * 4;
        #pragma unroll
        for (int j = 0; j < 4; ++j) {
            int col = col0 + wc + j*16 + (l & 15);
            float bv = bias ? bias[col] : 0.f;
            #pragma unroll
            for (int r = 0; r < 4; ++r) {
                int row = rbase + r;
                float val = acc[i][j][r] + bv;
                if (resid) val += resid[(size_t)row * ldc + col];
                if (relu)  val = fmaxf(val, 0.f);
                if (OUT_BF16) ((ushort*)Cb)[(size_t)row * ldc + col] = f2bf(val);
                else          ((float*)Cb)[(size_t)row * ldc + col]  = val;
            }
        }
    }
}

// ---------------------------------------------------------------------------
// 128x128 NT GEMM (kept for Wo: N=1024 -> 256 blocks). dbuf + swizzle.
// ---------------------------------------------------------------------------
template<int OUT_BF16>
__global__ __launch_bounds__(256) void gemm_nt_kernel(
    const ushort* __restrict__ A, int lda,
    const ushort* __restrict__ Bt, int ldb,
    void* __restrict__ C, int ldc, int K,
    const float* __restrict__ bias,
    const float* __restrict__ resid, int relu)
{
    __shared__ __attribute__((aligned(16))) ushort As[2][4][128][8];
    __shared__ __attribute__((aligned(16))) ushort Bs[2][4][128][8];

    int nwg  = gridDim.x * gridDim.y;
    int orig = blockIdx.y * gridDim.x + blockIdx.x;
    int work = (orig & 7) * (nwg >> 3) + (orig >> 3);
    int bx = work % gridDim.x, by = work / gridDim.x;

    int row0 = by * 128, col0 = bx * 128;
    int tid = threadIdx.x;
    int w = tid >> 6, l = tid & 63;
    int wr = (w >> 1) * 64, wc = (w & 1) * 64;

    int m0 = tid & 127, kc0 = tid >> 7;
    int m1 = (tid + 256) & 127, kc1 = (tid + 256) >> 7;
    const ushort* ga0 = A  + (size_t)(row0 + m0) * lda + kc0 * 8;
    const ushort* ga1 = A  + (size_t)(row0 + m1) * lda + kc1 * 8;
    const ushort* gb0 = Bt + (size_t)(col0 + m0) * ldb + kc0 * 8;
    const ushort* gb1 = Bt + (size_t)(col0 + m1) * ldb + kc1 * 8;

    f32x4 acc[4][4];
    #pragma unroll
    for (int i = 0; i < 4; ++i)
        #pragma unroll
        for (int j = 0; j < 4; ++j) acc[i][j] = (f32x4){0.f, 0.f, 0.f, 0.f};

    const int NT = K >> 5;
    g2l16(ga0, &As[0][kc0][m0][0]);
    g2l16(ga1, &As[0][kc1][m1][0]);
    g2l16(gb0, &Bs[0][kc0][m0][0]);
    g2l16(gb1, &Bs[0][kc1][m1][0]);
    __syncthreads();

    int cur = 0;
    for (int t = 0; t < NT; ++t) {
        if (t + 1 < NT) {
            int k0 = (t + 1) << 5;
            g2l16(ga0 + k0, &As[cur ^ 1][kc0][m0][0]);
            g2l16(ga1 + k0, &As[cur ^ 1][kc1][m1][0]);
            g2l16(gb0 + k0, &Bs[cur ^ 1][kc0][m0][0]);
            g2l16(gb1 + k0, &Bs[cur ^ 1][kc1][m1][0]);
        }
        int kc = l >> 4;
        bf16x8 af[4], bfr[4];
        #pragma unroll
        for (int i = 0; i < 4; ++i)
            af[i] = *(const bf16x8*)&As[cur][kc][wr + i*16 + (l & 15)][0];
        #pragma unroll
        for (int j = 0; j < 4; ++j)
            bfr[j] = *(const bf16x8*)&Bs[cur][kc][wc + j*16 + (l & 15)][0];
        #pragma unroll
        for (int i = 0; i < 4; ++i)
            #pragma unroll
            for (int j = 0; j < 4; ++j)
                acc[i][j] = __builtin_amdgcn_mfma_f32_16x16x32_bf16(
                    af[i], bfr[j], acc[i][j], 0, 0, 0);
        __syncthreads();
        cur ^= 1;
    }

    #pragma unroll
    for (int i = 0; i < 4; ++i) {
        int rbase = row0 + wr + i*16 + (l >> 4) * 4;
        #pragma unroll
        for (int j = 0; j < 4; ++j) {
            int col = col0 + wc + j*16 + (l & 15);
            float bv = bias ? bias[col] : 0.f;
            #pragma unroll
            for (int r = 0; r < 4; ++r) {
                int row = rbase + r;
                float val = acc[i][j][r] + bv;
                if (resid) val += resid[(size_t)row * ldc + col];
                if (relu)  val = fmaxf(val, 0.f);
                if (OUT_BF16) ((ushort*)C)[(size_t)row * ldc + col] = f2bf(val);
                else          ((float*)C)[(size_t)row * ldc + col]  = val;
            }
        }
    }
}

// ---------------------------------------------------------------------------
// colsum[s] = sum_q exp(q·k/8).  grid (T/128, B*H), 256 thr.
// qkv packed [bt][3072]: q at col 0, k at 1024, v at 2048 (+h*64).
// ---------------------------------------------------------------------------
__global__ __launch_bounds__(256) void csum_kernel(
    const ushort* __restrict__ qkv, float* __restrict__ col_sum)
{
    int bh = blockIdx.y, b = bh >> 4, h = bh & 15;
    int s0 = blockIdx.x * 128;
    const ushort* qb = qkv + (size_t)b * T_ * 3072 + h * 64;
    const ushort* kb = qb + 1024;
    __shared__ __attribute__((aligned(16))) ushort Ks[8][128][8];
    __shared__ __attribute__((aligned(16))) ushort Qs[8][64][8];
    int tid = threadIdx.x, w = tid >> 6, l = tid & 63;
    int scol = w * 32;

    #pragma unroll
    for (int p = 0; p < 4; ++p) {
        int idx = tid + p * 256;
        int s = idx & 127, kc = idx >> 7;
        *(uint4*)&Ks[kc][s][0] =
            *(const uint4*)(kb + (size_t)(s0 + s) * 3072 + kc * 8);
    }
    float cs[2] = {0.f, 0.f};
    for (int qt = 0; qt < T_ / 64; ++qt) {
        __syncthreads();
        #pragma unroll
        for (int p = 0; p < 2; ++p) {
            int idx = tid + p * 256;
            int qq = idx & 63, kc = idx >> 6;
            *(uint4*)&Qs[kc][qq][0] =
                *(const uint4*)(qb + (size_t)(qt*64 + qq) * 3072 + kc * 8);
        }
        __syncthreads();
        bf16x8 af[4][2], bfr[2][2];
        #pragma unroll
        for (int qi = 0; qi < 4; ++qi)
            #pragma unroll
            for (int ks = 0; ks < 2; ++ks)
                af[qi][ks] = *(const bf16x8*)&Qs[ks*4 + (l>>4)][qi*16 + (l & 15)][0];
        #pragma unroll
        for (int sj = 0; sj < 2; ++sj)
            #pragma unroll
            for (int ks = 0; ks < 2; ++ks)
                bfr[sj][ks] = *(const bf16x8*)&Ks[ks*4 + (l>>4)][scol + sj*16 + (l & 15)][0];
        #pragma unroll
        for (int qi = 0; qi < 4; ++qi)
            #pragma unroll
            for (int sj = 0; sj < 2; ++sj) {
                f32x4 d = (f32x4){0.f, 0.f, 0.f, 0.f};
                #pragma unroll
                for (int ks = 0; ks < 2; ++ks)
                    d = __builtin_amdgcn_mfma_f32_16x16x32_bf16(
                        af[qi][ks], bfr[sj][ks], d, 0, 0, 0);
                cs[sj] += __expf(d[0]*0.125f) + __expf(d[1]*0.125f)
                        + __expf(d[2]*0.125f) + __expf(d[3]*0.125f);
            }
    }
    #pragma unroll
    for (int sj = 0; sj < 2; ++sj) {
        float v = cs[sj];
        v += __shfl_down(v, 32, 64);
        v += __shfl_down(v, 16, 64);
        if (l < 16)
            col_sum[(size_t)bh * T_ + s0 + scol + sj*16 + l] = v;
    }
}

// ---------------------------------------------------------------------------
// vt[bh][dv][s] = v[bh][s][dv] / colsum[bh][s]   (bf16, transposed V)
// ---------------------------------------------------------------------------
__global__ __launch_bounds__(256) void vscale_kernel(
    const ushort* __restrict__ qkv, const float* __restrict__ col_sum,
    ushort* __restrict__ vt)
{
    int bh = blockIdx.y, b = bh >> 4, h = bh & 15;
    int s0 = blockIdx.x * 64;
    const ushort* vb = qkv + (size_t)b * T_ * 3072 + 2048 + h * 64;
    __shared__ float t[64][65];
    int tid = threadIdx.x;
    #pragma unroll
    for (int p = 0; p < 2; ++p) {
        int idx = tid + p * 256;
        int s = idx >> 3, c0 = (idx & 7) * 8;
        uint4 raw = *(const uint4*)(vb + (size_t)(s0 + s) * 3072 + c0);
        float rc = 1.0f / col_sum[(size_t)bh * T_ + s0 + s];
        ushort* u = (ushort*)&raw;
        #pragma unroll
        for (int i = 0; i < 8; ++i) t[s][c0 + i] = bf2f(u[i]) * rc;
    }
    __syncthreads();
    #pragma unroll
    for (int p = 0; p < 2; ++p) {
        int idx = tid + p * 256;
        int dv = idx >> 3, sc = (idx & 7) * 8;
        ushort o[8];
        #pragma unroll
        for (int i = 0; i < 8; ++i) o[i] = f2bf(t[sc + i][dv]);
        *(uint4*)(vt + ((size_t)bh * 64 + dv) * T_ + s0 + sc) = *(uint4*)o;
    }
}

// ---------------------------------------------------------------------------
// PV: O[q][dv] = sum_s exp(q·k/8) * vt[dv][s].  grid (T/64, B*H), 256 thr.
// ---------------------------------------------------------------------------
__global__ __launch_bounds__(256) void attn_pv_kernel(
    const ushort* __restrict__ qkv, const ushort* __restrict__ vt,
    ushort* __restrict__ attn_o)
{
    int bh = blockIdx.y, b = bh >> 4, h = bh & 15;
    int q0 = blockIdx.x * 64;
    const ushort* qb = qkv + (size_t)b * T_ * 3072 + h * 64;
    const ushort* kb = qb + 1024;
    const ushort* vtb = vt + (size_t)bh * 64 * T_;
    __shared__ __attribute__((aligned(16))) ushort Qs[8][64][8];
    __shared__ __attribute__((aligned(16))) ushort Ks[8][64][8];
    __shared__ __attribute__((aligned(16))) ushort Vs[8][64][8];
    __shared__ __attribute__((aligned(16))) ushort Es[8][64][8];
    int tid = threadIdx.x, w = tid >> 6, l = tid & 63;
    int qw = w * 16;

    #pragma unroll
    for (int p = 0; p < 2; ++p) {
        int idx = tid + p * 256;
        int qq = idx & 63, kc = idx >> 6;
        *(uint4*)&Qs[kc][qq][0] =
            *(const uint4*)(qb + (size_t)(q0 + qq) * 3072 + kc * 8);
    }
    __syncthreads();
    bf16x8 qf[2];
    #pragma unroll
    for (int ks = 0; ks < 2; ++ks)
        qf[ks] = *(const bf16x8*)&Qs[ks*4 + (l>>4)][qw + (l & 15)][0];

    f32x4 oacc[4];
    #pragma unroll
    for (int j = 0; j < 4; ++j) oacc[j] = (f32x4){0.f, 0.f, 0.f, 0.f};

    for (int st = 0; st < T_ / 64; ++st) {
        int s0 = st * 64;
        __syncthreads();
        #pragma unroll
        for (int p = 0; p < 2; ++p) {
            int idx = tid + p * 256;
            int rr = idx & 63, kc = idx >> 6;
            *(uint4*)&Ks[kc][rr][0] =
                *(const uint4*)(kb + (size_t)(s0 + rr) * 3072 + kc * 8);
            *(uint4*)&Vs[kc][rr][0] =
                *(const uint4*)(vtb + (size_t)rr * T_ + s0 + kc * 8);
        }
        __syncthreads();
        #pragma unroll
        for (int sj = 0; sj < 4; ++sj) {
            f32x4 d = (f32x4){0.f, 0.f, 0.f, 0.f};
            #pragma unroll
            for (int ks = 0; ks < 2; ++ks) {
                bf16x8 kf = *(const bf16x8*)&Ks[ks*4 + (l>>4)][sj*16 + (l & 15)][0];
                d = __builtin_amdgcn_mfma_f32_16x16x32_bf16(qf[ks], kf, d, 0, 0, 0);
            }
            #pragma unroll
            for (int r = 0; r < 4; ++r) {
                int qq = qw + (l>>4)*4 + r;
                int ss = sj*16 + (l & 15);
                Es[ss >> 3][qq][ss & 7] = f2bf(__expf(d[r] * 0.125f));
            }
        }
        bf16x8 ef[2];
        #pragma unroll
        for (int ks = 0; ks < 2; ++ks)
            ef[ks] = *(const bf16x8*)&Es[ks*4 + (l>>4)][qw + (l & 15)][0];
        #pragma unroll
        for (int j = 0; j < 4; ++j)
            #pragma unroll
            for (int ks = 0; ks < 2; ++ks) {
                bf16x8 vf = *(const bf16x8*)&Vs[ks*4 + (l>>4)][j*16 + (l & 15)][0];
                oacc[j] = __builtin_amdgcn_mfma_f32_16x16x32_bf16(ef[ks], vf, oacc[j], 0, 0, 0);
            }
    }
    #pragma unroll
    for (int j = 0; j < 4; ++j)
        #pragma unroll
        for (int r = 0; r < 4; ++r) {
            int qq = q0 + qw + (l>>4)*4 + r;
            int dv = j*16 + (l & 15);
            attn_o[(size_t)(b*T_ + qq) * 1024 + h*64 + dv] = f2bf(oacc[j][r]);
        }
}

// ---------------------------------------------------------------------------
// mean/std norm (Bessel), optional bf16 side-output.
// ---------------------------------------------------------------------------
__device__ __forceinline__ float block_reduce_sum_256(float v, float* tmp)
{
    #pragma unroll
    for (int off = 32; off; off >>= 1) v += __shfl_down(v, off, 64);
    int lane = threadIdx.x & 63, w = threadIdx.x >> 6;
    __syncthreads();
    if (lane == 0) tmp[w] = v;
    __syncthreads();
    return tmp[0] + tmp[1] + tmp[2] + tmp[3];
}

__global__ __launch_bounds__(256) void norm_kernel(
    const float* __restrict__ in, float* __restrict__ outf,
    ushort* __restrict__ outb)
{
    __shared__ float tmp[4];
    int row = blockIdx.x;
    const float* r = in + (size_t)row * D_;
    int tid = threadIdx.x;
    float vals[4];
    #pragma unroll
    for (int i = 0; i < 4; ++i) vals[i] = r[tid + i*256];
    float s = vals[0] + vals[1] + vals[2] + vals[3];
    s = block_reduce_sum_256(s, tmp);
    float m = s * (1.0f / (float)D_);
    float sq = 0.f;
    #pragma unroll
    for (int i = 0; i < 4; ++i) { float c = vals[i] - m; sq += c * c; }
    sq = block_reduce_sum_256(sq, tmp);
    float rs = rsqrtf(sq * (1.0f / (float)(D_ - 1)));
    #pragma unroll
    for (int i = 0; i < 4; ++i) {
        float o = (vals[i] - m) * rs;
        outf[(size_t)row * D_ + tid + i*256] = o;
        if (outb) outb[(size_t)row * D_ + tid + i*256] = f2bf(o);
    }
}

// ---------------------------------------------------------------------------
// norm2 fused: y = sum_{z<4} parts[z] (bf16 partials) + b2 + resid,
// then mean/std norm -> out f32. One block per row; thread owns cols 4t..4t+3.
// ---------------------------------------------------------------------------
__global__ __launch_bounds__(256) void norm2_fused_kernel(
    const ushort* __restrict__ parts, long zoff,
    const float* __restrict__ b2, const float* __restrict__ resid,
    float* __restrict__ outp)
{
    __shared__ float tmp[4];
    int row = blockIdx.x;
    int tid = threadIdx.x;
    int c0 = tid * 4;
    size_t idx = (size_t)row * D_ + c0;
    ushort4 p0 = *(const ushort4*)&parts[idx];
    ushort4 p1 = *(const ushort4*)&parts[idx + zoff];
    ushort4 p2 = *(const ushort4*)&parts[idx + 2*zoff];
    ushort4 p3 = *(const ushort4*)&parts[idx + 3*zoff];
    float4 rv = *(const float4*)&resid[idx];
    float4 bv = *(const float4*)&b2[c0];
    float vals[4];
    vals[0] = bf2f(p0.x) + bf2f(p1.x) + bf2f(p2.x) + bf2f(p3.x) + bv.x + rv.x;
    vals[1] = bf2f(p0.y) + bf2f(p1.y) + bf2f(p2.y) + bf2f(p3.y) + bv.y + rv.y;
    vals[2] = bf2f(p0.z) + bf2f(p1.z) + bf2f(p2.z) + bf2f(p3.z) + bv.z + rv.z;
    vals[3] = bf2f(p0.w) + bf2f(p1.w) + bf2f(p2.w) + bf2f(p3.w) + bv.w + rv.w;
    float s = vals[0] + vals[1] + vals[2] + vals[3];
    s = block_reduce_sum_256(s, tmp);
    float m = s * (1.0f / (float)D_);
    float sq = 0.f;
    #pragma unroll
    for (int i = 0; i < 4; ++i) { float c = vals[i] - m; sq += c * c; }
    sq = block_reduce_sum_256(sq, tmp);
    float rs = rsqrtf(sq * (1.0f / (float)(D_ - 1)));
    float4 o;
    o.x = (vals[0] - m) * rs; o.y = (vals[1] - m) * rs;
    o.z = (vals[2] - m) * rs; o.w = (vals[3] - m) * rs;
    *(float4*)&outp[idx] = o;
}

// ---------------------------------------------------------------------------
extern "C" void kernel_launch(void* const* d_in, const int* in_sizes, int n_in,
                              void* d_out, int out_size, void* d_ws, size_t ws_size,
                              hipStream_t stream)
{
    const float* x  = (const float*)d_in[0];
    const float* Wq = (const float*)d_in[1];
    const float* Wk = (const float*)d_in[2];
    const float* Wv = (const float*)d_in[3];
    const float* Wo = (const float*)d_in[4];
    const float* W1 = (const float*)d_in[5];
    const float* b1 = (const float*)d_in[6];
    const float* W2 = (const float*)d_in[7];
    const float* b2 = (const float*)d_in[8];
    float* out = (float*)d_out;

    const size_t MB = (size_t)1 << 20;
    char* base = (char*)d_ws;
    // lifetimes (total 122MB):
    ushort* qkv    = (ushort*)(base +   0*MB);  // 24MB  [QKV..PV]
    ushort* hid    = (ushort*)(base +   0*MB);  // 32MB  [W1..W2]   (reuses qkv+xb)
    ushort* xb     = (ushort*)(base +  24*MB);  //  8MB  [cvt..QKV]
    ushort* Wqkvt  = (ushort*)(base +  32*MB);  //  6MB  [cvt..QKV]
    ushort* wpart  = (ushort*)(base +  32*MB);  // 32MB  [W2..norm2] (reuses Wqkvt/vt/csum/Wot/W1t)
    ushort* vt     = (ushort*)(base +  38*MB);  //  8MB  [vscale..PV]
    float*  csum   = (float*) (base +  46*MB);  // .25MB [csum..vscale]
    ushort* Wot    = (ushort*)(base +  48*MB);  //  2MB  [cvt..Wo]
    ushort* W1t    = (ushort*)(base +  50*MB);  //  8MB  [cvt..W1]
    ushort* W2t    = (ushort*)(base +  66*MB);  //  8MB  [cvt..W2]
    ushort* attn_o = (ushort*)(base +  74*MB);  //  8MB  [PV..Wo]
    float*  oproj  = (float*) (base +  82*MB);  // 16MB  [Wo..norm1]
    float*  out1f  = (float*) (base +  98*MB);  // 16MB  [norm1..norm2]
    ushort* out1b  = (ushort*)(base + 114*MB);  //  8MB  [norm1..W1]

    // 1. converts / transposes
    cvt_bf16_kernel<<<dim3(BT_*D_/1024), 256, 0, stream>>>(x, xb, BT_*D_);
    transpose_bf16_kernel<<<dim3(2, 32, 16), 256, 0, stream>>>(
        Wq, Wqkvt + 0*1048576, 1024, 64, 65536, 65536);
    transpose_bf16_kernel<<<dim3(2, 32, 16), 256, 0, stream>>>(
        Wk, Wqkvt + 1*1048576, 1024, 64, 65536, 65536);
    transpose_bf16_kernel<<<dim3(2, 32, 16), 256, 0, stream>>>(
        Wv, Wqkvt + 2*1048576, 1024, 64, 65536, 65536);
    transpose_bf16_kernel<<<dim3(32, 32, 1), 256, 0, stream>>>(
        Wo, Wot, 1024, 1024, 0, 0);
    transpose_bf16_kernel<<<dim3(128, 32, 1), 256, 0, stream>>>(
        W1, W1t, 1024, 4096, 0, 0);
    transpose_bf16_kernel<<<dim3(32, 128, 1), 256, 0, stream>>>(
        W2, W2t, 4096, 1024, 0, 0);

    // 2. QKV: [4096,1024] @ [3072,1024]^T -> qkv bf16 [4096,3072]
    gemm256_kernel<1><<<dim3(3072/256, 4096/256, 1), 512, 0, stream>>>(
        xb, 1024, Wqkvt, 1024, qkv, 3072, 1024, nullptr, nullptr, 0, 0, 0, 0);
    // 3. column sums of exp(scores)
    csum_kernel<<<dim3(T_/128, B_*H_), 256, 0, stream>>>(qkv, csum);
    // 4. vt = (v/colsum)^T
    vscale_kernel<<<dim3(T_/64, B_*H_), 256, 0, stream>>>(qkv, csum, vt);
    // 5. PV
    attn_pv_kernel<<<dim3(T_/64, B_*H_), 256, 0, stream>>>(qkv, vt, attn_o);
    // 6. Wo projection + residual x -> oproj f32 (128^2 tile: 256 blocks)
    gemm_nt_kernel<0><<<dim3(1024/128, 4096/128), 256, 0, stream>>>(
        attn_o, 1024, Wot, 1024, oproj, 1024, 1024, nullptr, x, 0);
    // 7. norm1 -> out1f (f32) + out1b (bf16)
    norm_kernel<<<dim3(BT_), 256, 0, stream>>>(oproj, out1f, out1b);
    // 8. FFN up + ReLU -> hid bf16 [4096,4096]
    gemm256_kernel<1><<<dim3(4096/256, 4096/256, 1), 512, 0, stream>>>(
        out1b, 1024, W1t, 1024, hid, 4096, 1024, b1, nullptr, 1, 0, 0, 0);
    // 9. FFN down, split-K4 -> bf16 partials wpart[z][4096][1024]
    gemm256_kernel<1><<<dim3(1024/256, 4096/256, 4), 512, 0, stream>>>(
        hid, 4096, W2t, 4096, wpart, 1024, 1024, nullptr, nullptr, 0,
        1024, 1024, (long)4096*1024);
    // 10. norm2 fused: sum partials + b2 + out1 resid -> norm -> out
    norm2_fused_kernel<<<dim3(BT_), 256, 0, stream>>>(
        wpart, (long)4096*1024, b2, out1f, out);
}

// Round 6
// 474.846 us; speedup vs baseline: 5.3168x; 1.0031x over previous
//
#include <hip/hip_runtime.h>
#include <hip/hip_bf16.h>
#include <math.h>

#define B_  2
#define T_  2048
#define D_  1024
#define H_  16
#define DK_ 64
#define FF_ 4096
#define BT_ (B_*T_)

typedef __attribute__((ext_vector_type(8))) short bf16x8;
typedef __attribute__((ext_vector_type(4))) float f32x4;

__device__ __forceinline__ ushort f2bf(float f) {
    __hip_bfloat16 h = __float2bfloat16(f);
    return *reinterpret_cast<ushort*>(&h);
}
__device__ __forceinline__ float bf2f(ushort u) {
    __hip_bfloat16 h;
    *reinterpret_cast<ushort*>(&h) = u;
    return __bfloat162float(h);
}

// async global->LDS, 16B per lane. LDS dest must be wave-uniform base + lane*16.
__device__ __forceinline__ void g2l16(const ushort* g, ushort* l) {
    __builtin_amdgcn_global_load_lds(
        (const __attribute__((address_space(1))) void*)g,
        (__attribute__((address_space(3))) void*)l, 16, 0, 0);
}

// ---------------------------------------------------------------------------
// f32 -> bf16 elementwise (vectorized, n multiple of 1024)
// ---------------------------------------------------------------------------
__global__ __launch_bounds__(256) void cvt_bf16_kernel(
    const float* __restrict__ in, ushort* __restrict__ out, int n)
{
    int i = (blockIdx.x * 256 + threadIdx.x) * 4;
    if (i >= n) return;
    float4 v = *(const float4*)(in + i);
    ushort4 o;
    o.x = f2bf(v.x); o.y = f2bf(v.y); o.z = f2bf(v.z); o.w = f2bf(v.w);
    *(ushort4*)(out + i) = o;
}

// ---------------------------------------------------------------------------
// transpose + convert: in f32 [K][N] -> out bf16 [N][K]; batched over z.
// ---------------------------------------------------------------------------
__global__ __launch_bounds__(256) void transpose_bf16_kernel(
    const float* __restrict__ in, ushort* __restrict__ out,
    int K, int N, long in_bstride, long out_bstride)
{
    __shared__ float t[32][33];
    const float* ib = in + (size_t)blockIdx.z * in_bstride;
    ushort* ob = out + (size_t)blockIdx.z * out_bstride;
    int n0 = blockIdx.x * 32, k0 = blockIdx.y * 32;
    int tid = threadIdx.x;
    int r = tid >> 3, c4 = (tid & 7) * 4;
    float4 v = *(const float4*)(ib + (size_t)(k0 + r) * N + n0 + c4);
    t[r][c4] = v.x; t[r][c4+1] = v.y; t[r][c4+2] = v.z; t[r][c4+3] = v.w;
    __syncthreads();
    int n = tid >> 3, kc = (tid & 7) * 4;
    ushort4 o;
    o.x = f2bf(t[kc+0][n]); o.y = f2bf(t[kc+1][n]);
    o.z = f2bf(t[kc+2][n]); o.w = f2bf(t[kc+3][n]);
    *(ushort4*)(ob + (size_t)(n0 + n) * K + k0 + kc) = o;
}

// ---------------------------------------------------------------------------
// 256x256-tile NT GEMM, bf16 MFMA, BK=64, 512 threads (8 waves, 2Mx4N).
// Depth-2 counted-vmcnt pipeline, two raw barriers per K-tile:
//   prologue: stage tiles 0,1 (16 loads/thread-wave in flight)
//   iter t:   vmcnt(8) [tile t landed, t+1 flying] -> barrier (publish)
//             -> MFMA on buf[t&1] -> barrier (WAR) -> stage t+2 -> buf[t&1]
// vmcnt never drains to 0 in the main loop (T4).
// ---------------------------------------------------------------------------
template<int OUT_BF16>
__global__ __launch_bounds__(512) void gemm256_kernel(
    const ushort* __restrict__ A, int lda,
    const ushort* __restrict__ Bt, int ldb,
    void* __restrict__ C, int ldc, int K,
    const float* __restrict__ bias,
    const float* __restrict__ resid, int relu,
    long aZoff, long bZoff, long cZoff)
{
    __shared__ __attribute__((aligned(16))) ushort As[2][8][256][8];
    __shared__ __attribute__((aligned(16))) ushort Bs[2][8][256][8];

    A  += (size_t)blockIdx.z * aZoff;
    Bt += (size_t)blockIdx.z * bZoff;
    char* Cb = (char*)C + (size_t)blockIdx.z * cZoff * (OUT_BF16 ? 2 : 4);

    // XCD swizzle over x,y (nwg per z-slice must be %8==0 -- true here)
    int nwg  = gridDim.x * gridDim.y;
    int orig = blockIdx.y * gridDim.x + blockIdx.x;
    int work = (orig & 7) * (nwg >> 3) + (orig >> 3);
    int bx = work % gridDim.x, by = work / gridDim.x;

    int row0 = by * 256, col0 = bx * 256;
    int tid = threadIdx.x;
    int l = tid & 63;
    int w = tid >> 6;
    int wr = (w >> 2) * 128, wc = (w & 3) * 64;

    // staging coords: m const per thread, kc = kc0 + 2p
    int m = tid & 255, kc0 = tid >> 8;
    const ushort* gA = A  + (size_t)(row0 + m) * lda + kc0 * 8;
    const ushort* gB = Bt + (size_t)(col0 + m) * ldb + kc0 * 8;

    f32x4 acc[8][4];
    #pragma unroll
    for (int i = 0; i < 8; ++i)
        #pragma unroll
        for (int j = 0; j < 4; ++j) acc[i][j] = (f32x4){0.f, 0.f, 0.f, 0.f};

    const int NT = K >> 6;

    // prologue: stage tiles 0 and 1
    #pragma unroll
    for (int p = 0; p < 4; ++p) {
        g2l16(gA + p*16, &As[0][kc0 + 2*p][m][0]);
        g2l16(gB + p*16, &Bs[0][kc0 + 2*p][m][0]);
    }
    if (NT > 1) {
        #pragma unroll
        for (int p = 0; p < 4; ++p) {
            g2l16(gA + 64 + p*16, &As[1][kc0 + 2*p][m][0]);
            g2l16(gB + 64 + p*16, &Bs[1][kc0 + 2*p][m][0]);
        }
    }

    for (int t = 0; t < NT; ++t) {
        int cur = t & 1;
        if (t + 1 < NT) asm volatile("s_waitcnt vmcnt(8)" ::: "memory");
        else            asm volatile("s_waitcnt vmcnt(0)" ::: "memory");
        __builtin_amdgcn_sched_barrier(0);
        __builtin_amdgcn_s_barrier();            // (a) tile t published
        __builtin_amdgcn_sched_barrier(0);

        __builtin_amdgcn_s_setprio(1);
        #pragma unroll
        for (int ks = 0; ks < 2; ++ks) {
            bf16x8 bfr[4];
            #pragma unroll
            for (int j = 0; j < 4; ++j)
                bfr[j] = *(const bf16x8*)&Bs[cur][ks*4 + (l>>4)][wc + j*16 + (l & 15)][0];
            #pragma unroll
            for (int i = 0; i < 8; ++i) {
                bf16x8 a = *(const bf16x8*)&As[cur][ks*4 + (l>>4)][wr + i*16 + (l & 15)][0];
                #pragma unroll
                for (int j = 0; j < 4; ++j)
                    acc[i][j] = __builtin_amdgcn_mfma_f32_16x16x32_bf16(
                        a, bfr[j], acc[i][j], 0, 0, 0);
            }
        }
        __builtin_amdgcn_s_setprio(0);

        __builtin_amdgcn_sched_barrier(0);
        __builtin_amdgcn_s_barrier();            // (b) all waves consumed buf[cur]
        __builtin_amdgcn_sched_barrier(0);

        if (t + 2 < NT) {                        // stage tile t+2 into buf[cur]
            int k0 = (t + 2) << 6;
            #pragma unroll
            for (int p = 0; p < 4; ++p) {
                g2l16(gA + k0 + p*16, &As[cur][kc0 + 2*p][m][0]);
                g2l16(gB + k0 + p*16, &Bs[cur][kc0 + 2*p][m][0]);
            }
        }
    }

    #pragma unroll
    for (int i = 0; i < 8; ++i) {
        int rbase = row0 + wr + i*16 + (l >> 4) * 4;
        #pragma unroll
        for (int j = 0; j < 4; ++j) {
            int col = col0 + wc + j*16 + (l & 15);
            float bv = bias ? bias[col] : 0.f;
            #pragma unroll
            for (int r = 0; r < 4; ++r) {
                int row = rbase + r;
                float val = acc[i][j][r] + bv;
                if (resid) val += resid[(size_t)row * ldc + col];
                if (relu)  val = fmaxf(val, 0.f);
                if (OUT_BF16) ((ushort*)Cb)[(size_t)row * ldc + col] = f2bf(val);
                else          ((float*)Cb)[(size_t)row * ldc + col]  = val;
            }
        }
    }
}

// ---------------------------------------------------------------------------
// 128x128 NT GEMM (kept for Wo: N=1024 -> 256 blocks). Same counted pipeline,
// vmcnt(4) steady-state.
// ---------------------------------------------------------------------------
template<int OUT_BF16>
__global__ __launch_bounds__(256) void gemm_nt_kernel(
    const ushort* __restrict__ A, int lda,
    const ushort* __restrict__ Bt, int ldb,
    void* __restrict__ C, int ldc, int K,
    const float* __restrict__ bias,
    const float* __restrict__ resid, int relu)
{
    __shared__ __attribute__((aligned(16))) ushort As[2][4][128][8];
    __shared__ __attribute__((aligned(16))) ushort Bs[2][4][128][8];

    int nwg  = gridDim.x * gridDim.y;
    int orig = blockIdx.y * gridDim.x + blockIdx.x;
    int work = (orig & 7) * (nwg >> 3) + (orig >> 3);
    int bx = work % gridDim.x, by = work / gridDim.x;

    int row0 = by * 128, col0 = bx * 128;
    int tid = threadIdx.x;
    int w = tid >> 6, l = tid & 63;
    int wr = (w >> 1) * 64, wc = (w & 1) * 64;

    int m0 = tid & 127, kc0 = tid >> 7;
    int m1 = (tid + 256) & 127, kc1 = (tid + 256) >> 7;
    const ushort* ga0 = A  + (size_t)(row0 + m0) * lda + kc0 * 8;
    const ushort* ga1 = A  + (size_t)(row0 + m1) * lda + kc1 * 8;
    const ushort* gb0 = Bt + (size_t)(col0 + m0) * ldb + kc0 * 8;
    const ushort* gb1 = Bt + (size_t)(col0 + m1) * ldb + kc1 * 8;

    f32x4 acc[4][4];
    #pragma unroll
    for (int i = 0; i < 4; ++i)
        #pragma unroll
        for (int j = 0; j < 4; ++j) acc[i][j] = (f32x4){0.f, 0.f, 0.f, 0.f};

    const int NT = K >> 5;

    g2l16(ga0, &As[0][kc0][m0][0]);
    g2l16(ga1, &As[0][kc1][m1][0]);
    g2l16(gb0, &Bs[0][kc0][m0][0]);
    g2l16(gb1, &Bs[0][kc1][m1][0]);
    if (NT > 1) {
        g2l16(ga0 + 32, &As[1][kc0][m0][0]);
        g2l16(ga1 + 32, &As[1][kc1][m1][0]);
        g2l16(gb0 + 32, &Bs[1][kc0][m0][0]);
        g2l16(gb1 + 32, &Bs[1][kc1][m1][0]);
    }

    for (int t = 0; t < NT; ++t) {
        int cur = t & 1;
        if (t + 1 < NT) asm volatile("s_waitcnt vmcnt(4)" ::: "memory");
        else            asm volatile("s_waitcnt vmcnt(0)" ::: "memory");
        __builtin_amdgcn_sched_barrier(0);
        __builtin_amdgcn_s_barrier();
        __builtin_amdgcn_sched_barrier(0);

        __builtin_amdgcn_s_setprio(1);
        int kc = l >> 4;
        bf16x8 af[4], bfr[4];
        #pragma unroll
        for (int i = 0; i < 4; ++i)
            af[i] = *(const bf16x8*)&As[cur][kc][wr + i*16 + (l & 15)][0];
        #pragma unroll
        for (int j = 0; j < 4; ++j)
            bfr[j] = *(const bf16x8*)&Bs[cur][kc][wc + j*16 + (l & 15)][0];
        #pragma unroll
        for (int i = 0; i < 4; ++i)
            #pragma unroll
            for (int j = 0; j < 4; ++j)
                acc[i][j] = __builtin_amdgcn_mfma_f32_16x16x32_bf16(
                    af[i], bfr[j], acc[i][j], 0, 0, 0);
        __builtin_amdgcn_s_setprio(0);

        __builtin_amdgcn_sched_barrier(0);
        __builtin_amdgcn_s_barrier();
        __builtin_amdgcn_sched_barrier(0);

        if (t + 2 < NT) {
            int k0 = (t + 2) << 5;
            g2l16(ga0 + k0, &As[cur][kc0][m0][0]);
            g2l16(ga1 + k0, &As[cur][kc1][m1][0]);
            g2l16(gb0 + k0, &Bs[cur][kc0][m0][0]);
            g2l16(gb1 + k0, &Bs[cur][kc1][m1][0]);
        }
    }

    #pragma unroll
    for (int i = 0; i < 4; ++i) {
        int rbase = row0 + wr + i*16 + (l >> 4) * 4;
        #pragma unroll
        for (int j = 0; j < 4; ++j) {
            int col = col0 + wc + j*16 + (l & 15);
            float bv = bias ? bias[col] : 0.f;
            #pragma unroll
            for (int r = 0; r < 4; ++r) {
                int row = rbase + r;
                float val = acc[i][j][r] + bv;
                if (resid) val += resid[(size_t)row * ldc + col];
                if (relu)  val = fmaxf(val, 0.f);
                if (OUT_BF16) ((ushort*)C)[(size_t)row * ldc + col] = f2bf(val);
                else          ((float*)C)[(size_t)row * ldc + col]  = val;
            }
        }
    }
}

// ---------------------------------------------------------------------------
// colsum[s] = sum_q exp(q·k/8).  grid (T/128, B*H), 256 thr.
// qkv packed [bt][3072]: q at col 0, k at 1024, v at 2048 (+h*64).
// ---------------------------------------------------------------------------
__global__ __launch_bounds__(256) void csum_kernel(
    const ushort* __restrict__ qkv, float* __restrict__ col_sum)
{
    int bh = blockIdx.y, b = bh >> 4, h = bh & 15;
    int s0 = blockIdx.x * 128;
    const ushort* qb = qkv + (size_t)b * T_ * 3072 + h * 64;
    const ushort* kb = qb + 1024;
    __shared__ __attribute__((aligned(16))) ushort Ks[8][128][8];
    __shared__ __attribute__((aligned(16))) ushort Qs[8][64][8];
    int tid = threadIdx.x, w = tid >> 6, l = tid & 63;
    int scol = w * 32;

    #pragma unroll
    for (int p = 0; p < 4; ++p) {
        int idx = tid + p * 256;
        int s = idx & 127, kc = idx >> 7;
        *(uint4*)&Ks[kc][s][0] =
            *(const uint4*)(kb + (size_t)(s0 + s) * 3072 + kc * 8);
    }
    float cs[2] = {0.f, 0.f};
    for (int qt = 0; qt < T_ / 64; ++qt) {
        __syncthreads();
        #pragma unroll
        for (int p = 0; p < 2; ++p) {
            int idx = tid + p * 256;
            int qq = idx & 63, kc = idx >> 6;
            *(uint4*)&Qs[kc][qq][0] =
                *(const uint4*)(qb + (size_t)(qt*64 + qq) * 3072 + kc * 8);
        }
        __syncthreads();
        bf16x8 af[4][2], bfr[2][2];
        #pragma unroll
        for (int qi = 0; qi < 4; ++qi)
            #pragma unroll
            for (int ks = 0; ks < 2; ++ks)
                af[qi][ks] = *(const bf16x8*)&Qs[ks*4 + (l>>4)][qi*16 + (l & 15)][0];
        #pragma unroll
        for (int sj = 0; sj < 2; ++sj)
            #pragma unroll
            for (int ks = 0; ks < 2; ++ks)
                bfr[sj][ks] = *(const bf16x8*)&Ks[ks*4 + (l>>4)][scol + sj*16 + (l & 15)][0];
        #pragma unroll
        for (int qi = 0; qi < 4; ++qi)
            #pragma unroll
            for (int sj = 0; sj < 2; ++sj) {
                f32x4 d = (f32x4){0.f, 0.f, 0.f, 0.f};
                #pragma unroll
                for (int ks = 0; ks < 2; ++ks)
                    d = __builtin_amdgcn_mfma_f32_16x16x32_bf16(
                        af[qi][ks], bfr[sj][ks], d, 0, 0, 0);
                cs[sj] += __expf(d[0]*0.125f) + __expf(d[1]*0.125f)
                        + __expf(d[2]*0.125f) + __expf(d[3]*0.125f);
            }
    }
    #pragma unroll
    for (int sj = 0; sj < 2; ++sj) {
        float v = cs[sj];
        v += __shfl_down(v, 32, 64);
        v += __shfl_down(v, 16, 64);
        if (l < 16)
            col_sum[(size_t)bh * T_ + s0 + scol + sj*16 + l] = v;
    }
}

// ---------------------------------------------------------------------------
// vt[bh][dv][s] = v[bh][s][dv] / colsum[bh][s]   (bf16, transposed V)
// ---------------------------------------------------------------------------
__global__ __launch_bounds__(256) void vscale_kernel(
    const ushort* __restrict__ qkv, const float* __restrict__ col_sum,
    ushort* __restrict__ vt)
{
    int bh = blockIdx.y, b = bh >> 4, h = bh & 15;
    int s0 = blockIdx.x * 64;
    const ushort* vb = qkv + (size_t)b * T_ * 3072 + 2048 + h * 64;
    __shared__ float t[64][65];
    int tid = threadIdx.x;
    #pragma unroll
    for (int p = 0; p < 2; ++p) {
        int idx = tid + p * 256;
        int s = idx >> 3, c0 = (idx & 7) * 8;
        uint4 raw = *(const uint4*)(vb + (size_t)(s0 + s) * 3072 + c0);
        float rc = 1.0f / col_sum[(size_t)bh * T_ + s0 + s];
        ushort* u = (ushort*)&raw;
        #pragma unroll
        for (int i = 0; i < 8; ++i) t[s][c0 + i] = bf2f(u[i]) * rc;
    }
    __syncthreads();
    #pragma unroll
    for (int p = 0; p < 2; ++p) {
        int idx = tid + p * 256;
        int dv = idx >> 3, sc = (idx & 7) * 8;
        ushort o[8];
        #pragma unroll
        for (int i = 0; i < 8; ++i) o[i] = f2bf(t[sc + i][dv]);
        *(uint4*)(vt + ((size_t)bh * 64 + dv) * T_ + s0 + sc) = *(uint4*)o;
    }
}

// ---------------------------------------------------------------------------
// PV: O[q][dv] = sum_s exp(q·k/8) * vt[dv][s].  grid (T/64, B*H), 256 thr.
// ---------------------------------------------------------------------------
__global__ __launch_bounds__(256) void attn_pv_kernel(
    const ushort* __restrict__ qkv, const ushort* __restrict__ vt,
    ushort* __restrict__ attn_o)
{
    int bh = blockIdx.y, b = bh >> 4, h = bh & 15;
    int q0 = blockIdx.x * 64;
    const ushort* qb = qkv + (size_t)b * T_ * 3072 + h * 64;
    const ushort* kb = qb + 1024;
    const ushort* vtb = vt + (size_t)bh * 64 * T_;
    __shared__ __attribute__((aligned(16))) ushort Qs[8][64][8];
    __shared__ __attribute__((aligned(16))) ushort Ks[8][64][8];
    __shared__ __attribute__((aligned(16))) ushort Vs[8][64][8];
    __shared__ __attribute__((aligned(16))) ushort Es[8][64][8];
    int tid = threadIdx.x, w = tid >> 6, l = tid & 63;
    int qw = w * 16;

    #pragma unroll
    for (int p = 0; p < 2; ++p) {
        int idx = tid + p * 256;
        int qq = idx & 63, kc = idx >> 6;
        *(uint4*)&Qs[kc][qq][0] =
            *(const uint4*)(qb + (size_t)(q0 + qq) * 3072 + kc * 8);
    }
    __syncthreads();
    bf16x8 qf[2];
    #pragma unroll
    for (int ks = 0; ks < 2; ++ks)
        qf[ks] = *(const bf16x8*)&Qs[ks*4 + (l>>4)][qw + (l & 15)][0];

    f32x4 oacc[4];
    #pragma unroll
    for (int j = 0; j < 4; ++j) oacc[j] = (f32x4){0.f, 0.f, 0.f, 0.f};

    for (int st = 0; st < T_ / 64; ++st) {
        int s0 = st * 64;
        __syncthreads();
        #pragma unroll
        for (int p = 0; p < 2; ++p) {
            int idx = tid + p * 256;
            int rr = idx & 63, kc = idx >> 6;
            *(uint4*)&Ks[kc][rr][0] =
                *(const uint4*)(kb + (size_t)(s0 + rr) * 3072 + kc * 8);
            *(uint4*)&Vs[kc][rr][0] =
                *(const uint4*)(vtb + (size_t)rr * T_ + s0 + kc * 8);
        }
        __syncthreads();
        #pragma unroll
        for (int sj = 0; sj < 4; ++sj) {
            f32x4 d = (f32x4){0.f, 0.f, 0.f, 0.f};
            #pragma unroll
            for (int ks = 0; ks < 2; ++ks) {
                bf16x8 kf = *(const bf16x8*)&Ks[ks*4 + (l>>4)][sj*16 + (l & 15)][0];
                d = __builtin_amdgcn_mfma_f32_16x16x32_bf16(qf[ks], kf, d, 0, 0, 0);
            }
            #pragma unroll
            for (int r = 0; r < 4; ++r) {
                int qq = qw + (l>>4)*4 + r;
                int ss = sj*16 + (l & 15);
                Es[ss >> 3][qq][ss & 7] = f2bf(__expf(d[r] * 0.125f));
            }
        }
        bf16x8 ef[2];
        #pragma unroll
        for (int ks = 0; ks < 2; ++ks)
            ef[ks] = *(const bf16x8*)&Es[ks*4 + (l>>4)][qw + (l & 15)][0];
        #pragma unroll
        for (int j = 0; j < 4; ++j)
            #pragma unroll
            for (int ks = 0; ks < 2; ++ks) {
                bf16x8 vf = *(const bf16x8*)&Vs[ks*4 + (l>>4)][j*16 + (l & 15)][0];
                oacc[j] = __builtin_amdgcn_mfma_f32_16x16x32_bf16(ef[ks], vf, oacc[j], 0, 0, 0);
            }
    }
    #pragma unroll
    for (int j = 0; j < 4; ++j)
        #pragma unroll
        for (int r = 0; r < 4; ++r) {
            int qq = q0 + qw + (l>>4)*4 + r;
            int dv = j*16 + (l & 15);
            attn_o[(size_t)(b*T_ + qq) * 1024 + h*64 + dv] = f2bf(oacc[j][r]);
        }
}

// ---------------------------------------------------------------------------
// mean/std norm (Bessel), optional bf16 side-output.
// ---------------------------------------------------------------------------
__device__ __forceinline__ float block_reduce_sum_256(float v, float* tmp)
{
    #pragma unroll
    for (int off = 32; off; off >>= 1) v += __shfl_down(v, off, 64);
    int lane = threadIdx.x & 63, w = threadIdx.x >> 6;
    __syncthreads();
    if (lane == 0) tmp[w] = v;
    __syncthreads();
    return tmp[0] + tmp[1] + tmp[2] + tmp[3];
}

__global__ __launch_bounds__(256) void norm_kernel(
    const float* __restrict__ in, float* __restrict__ outf,
    ushort* __restrict__ outb)
{
    __shared__ float tmp[4];
    int row = blockIdx.x;
    const float* r = in + (size_t)row * D_;
    int tid = threadIdx.x;
    float vals[4];
    #pragma unroll
    for (int i = 0; i < 4; ++i) vals[i] = r[tid + i*256];
    float s = vals[0] + vals[1] + vals[2] + vals[3];
    s = block_reduce_sum_256(s, tmp);
    float m = s * (1.0f / (float)D_);
    float sq = 0.f;
    #pragma unroll
    for (int i = 0; i < 4; ++i) { float c = vals[i] - m; sq += c * c; }
    sq = block_reduce_sum_256(sq, tmp);
    float rs = rsqrtf(sq * (1.0f / (float)(D_ - 1)));
    #pragma unroll
    for (int i = 0; i < 4; ++i) {
        float o = (vals[i] - m) * rs;
        outf[(size_t)row * D_ + tid + i*256] = o;
        if (outb) outb[(size_t)row * D_ + tid + i*256] = f2bf(o);
    }
}

// ---------------------------------------------------------------------------
// norm2 fused: y = sum_{z<4} parts[z] (bf16 partials) + b2 + resid,
// then mean/std norm -> out f32. One block per row; thread owns cols 4t..4t+3.
// ---------------------------------------------------------------------------
__global__ __launch_bounds__(256) void norm2_fused_kernel(
    const ushort* __restrict__ parts, long zoff,
    const float* __restrict__ b2, const float* __restrict__ resid,
    float* __restrict__ outp)
{
    __shared__ float tmp[4];
    int row = blockIdx.x;
    int tid = threadIdx.x;
    int c0 = tid * 4;
    size_t idx = (size_t)row * D_ + c0;
    ushort4 p0 = *(const ushort4*)&parts[idx];
    ushort4 p1 = *(const ushort4*)&parts[idx + zoff];
    ushort4 p2 = *(const ushort4*)&parts[idx + 2*zoff];
    ushort4 p3 = *(const ushort4*)&parts[idx + 3*zoff];
    float4 rv = *(const float4*)&resid[idx];
    float4 bv = *(const float4*)&b2[c0];
    float vals[4];
    vals[0] = bf2f(p0.x) + bf2f(p1.x) + bf2f(p2.x) + bf2f(p3.x) + bv.x + rv.x;
    vals[1] = bf2f(p0.y) + bf2f(p1.y) + bf2f(p2.y) + bf2f(p3.y) + bv.y + rv.y;
    vals[2] = bf2f(p0.z) + bf2f(p1.z) + bf2f(p2.z) + bf2f(p3.z) + bv.z + rv.z;
    vals[3] = bf2f(p0.w) + bf2f(p1.w) + bf2f(p2.w) + bf2f(p3.w) + bv.w + rv.w;
    float s = vals[0] + vals[1] + vals[2] + vals[3];
    s = block_reduce_sum_256(s, tmp);
    float m = s * (1.0f / (float)D_);
    float sq = 0.f;
    #pragma unroll
    for (int i = 0; i < 4; ++i) { float c = vals[i] - m; sq += c * c; }
    sq = block_reduce_sum_256(sq, tmp);
    float rs = rsqrtf(sq * (1.0f / (float)(D_ - 1)));
    float4 o;
    o.x = (vals[0] - m) * rs; o.y = (vals[1] - m) * rs;
    o.z = (vals[2] - m) * rs; o.w = (vals[3] - m) * rs;
    *(float4*)&outp[idx] = o;
}

// ---------------------------------------------------------------------------
extern "C" void kernel_launch(void* const* d_in, const int* in_sizes, int n_in,
                              void* d_out, int out_size, void* d_ws, size_t ws_size,
                              hipStream_t stream)
{
    const float* x  = (const float*)d_in[0];
    const float* Wq = (const float*)d_in[1];
    const float* Wk = (const float*)d_in[2];
    const float* Wv = (const float*)d_in[3];
    const float* Wo = (const float*)d_in[4];
    const float* W1 = (const float*)d_in[5];
    const float* b1 = (const float*)d_in[6];
    const float* W2 = (const float*)d_in[7];
    const float* b2 = (const float*)d_in[8];
    float* out = (float*)d_out;

    const size_t MB = (size_t)1 << 20;
    char* base = (char*)d_ws;
    // lifetimes (total 122MB):
    ushort* qkv    = (ushort*)(base +   0*MB);  // 24MB  [QKV..PV]
    ushort* hid    = (ushort*)(base +   0*MB);  // 32MB  [W1..W2]   (reuses qkv+xb)
    ushort* xb     = (ushort*)(base +  24*MB);  //  8MB  [cvt..QKV]
    ushort* Wqkvt  = (ushort*)(base +  32*MB);  //  6MB  [cvt..QKV]
    ushort* wpart  = (ushort*)(base +  32*MB);  // 32MB  [W2..norm2] (reuses Wqkvt/vt/csum/Wot/W1t)
    ushort* vt     = (ushort*)(base +  38*MB);  //  8MB  [vscale..PV]
    float*  csum   = (float*) (base +  46*MB);  // .25MB [csum..vscale]
    ushort* Wot    = (ushort*)(base +  48*MB);  //  2MB  [cvt..Wo]
    ushort* W1t    = (ushort*)(base +  50*MB);  //  8MB  [cvt..W1]
    ushort* W2t    = (ushort*)(base +  66*MB);  //  8MB  [cvt..W2]
    ushort* attn_o = (ushort*)(base +  74*MB);  //  8MB  [PV..Wo]
    float*  oproj  = (float*) (base +  82*MB);  // 16MB  [Wo..norm1]
    float*  out1f  = (float*) (base +  98*MB);  // 16MB  [norm1..norm2]
    ushort* out1b  = (ushort*)(base + 114*MB);  //  8MB  [norm1..W1]

    // 1. converts / transposes
    cvt_bf16_kernel<<<dim3(BT_*D_/1024), 256, 0, stream>>>(x, xb, BT_*D_);
    transpose_bf16_kernel<<<dim3(2, 32, 16), 256, 0, stream>>>(
        Wq, Wqkvt + 0*1048576, 1024, 64, 65536, 65536);
    transpose_bf16_kernel<<<dim3(2, 32, 16), 256, 0, stream>>>(
        Wk, Wqkvt + 1*1048576, 1024, 64, 65536, 65536);
    transpose_bf16_kernel<<<dim3(2, 32, 16), 256, 0, stream>>>(
        Wv, Wqkvt + 2*1048576, 1024, 64, 65536, 65536);
    transpose_bf16_kernel<<<dim3(32, 32, 1), 256, 0, stream>>>(
        Wo, Wot, 1024, 1024, 0, 0);
    transpose_bf16_kernel<<<dim3(128, 32, 1), 256, 0, stream>>>(
        W1, W1t, 1024, 4096, 0, 0);
    transpose_bf16_kernel<<<dim3(32, 128, 1), 256, 0, stream>>>(
        W2, W2t, 4096, 1024, 0, 0);

    // 2. QKV: [4096,1024] @ [3072,1024]^T -> qkv bf16 [4096,3072]
    gemm256_kernel<1><<<dim3(3072/256, 4096/256, 1), 512, 0, stream>>>(
        xb, 1024, Wqkvt, 1024, qkv, 3072, 1024, nullptr, nullptr, 0, 0, 0, 0);
    // 3. column sums of exp(scores)
    csum_kernel<<<dim3(T_/128, B_*H_), 256, 0, stream>>>(qkv, csum);
    // 4. vt = (v/colsum)^T
    vscale_kernel<<<dim3(T_/64, B_*H_), 256, 0, stream>>>(qkv, csum, vt);
    // 5. PV
    attn_pv_kernel<<<dim3(T_/64, B_*H_), 256, 0, stream>>>(qkv, vt, attn_o);
    // 6. Wo projection + residual x -> oproj f32 (128^2 tile: 256 blocks)
    gemm_nt_kernel<0><<<dim3(1024/128, 4096/128), 256, 0, stream>>>(
        attn_o, 1024, Wot, 1024, oproj, 1024, 1024, nullptr, x, 0);
    // 7. norm1 -> out1f (f32) + out1b (bf16)
    norm_kernel<<<dim3(BT_), 256, 0, stream>>>(oproj, out1f, out1b);
    // 8. FFN up + ReLU -> hid bf16 [4096,4096]
    gemm256_kernel<1><<<dim3(4096/256, 4096/256, 1), 512, 0, stream>>>(
        out1b, 1024, W1t, 1024, hid, 4096, 1024, b1, nullptr, 1, 0, 0, 0);
    // 9. FFN down, split-K4 -> bf16 partials wpart[z][4096][1024]
    gemm256_kernel<1><<<dim3(1024/256, 4096/256, 4), 512, 0, stream>>>(
        hid, 4096, W2t, 4096, wpart, 1024, 1024, nullptr, nullptr, 0,
        1024, 1024, (long)4096*1024);
    // 10. norm2 fused: sum partials + b2 + out1 resid -> norm -> out
    norm2_fused_kernel<<<dim3(BT_), 256, 0, stream>>>(
        wpart, (long)4096*1024, b2, out1f, out);
}